// Round 12
// baseline (446.278 us; speedup 1.0000x reference)
//
#include <hip/hip_runtime.h>
#include <math.h>

#define N_NODES 32768
#define N_EDGES 524288
#define NODE_DIM 128
#define HIDDEN 256
#define EDGE_DIM 32
#define TE 32              // edges per block
#define NBLK (N_EDGES / TE)
#define ASTR 296           // fallback smA row stride (bf16)
#define HSTR 264           // fallback smH row stride (bf16)
#define SZ2  264           // pp smZ/smH row stride (bf16): 528 B, 16B-aligned
#define MSTR 132           // smM row stride (f32): 528 B, 16B-aligned

typedef __attribute__((ext_vector_type(8))) short bf16x8;
typedef __attribute__((ext_vector_type(16))) float f32x16;

__device__ __forceinline__ float silu_f(float v) {
    float e = __expf(-v);
    return v * __builtin_amdgcn_rcpf(1.0f + e);
}

__device__ __forceinline__ unsigned short f2bf_rne(float f) {
    union { float f; unsigned int u; } v; v.f = f;
    return (unsigned short)((v.u + 0x7fffu + ((v.u >> 16) & 1u)) >> 16);
}
__device__ __forceinline__ unsigned int pk_rne(float a, float b) {
    return (unsigned int)f2bf_rne(a) | ((unsigned int)f2bf_rne(b) << 16);
}
// half-up pack of two floats -> (bf16(a) | bf16(b)<<16)
__device__ __forceinline__ unsigned int pkbf(float a, float b) {
    union { float f; unsigned int u; } ua, ub; ua.f = a; ub.f = b;
    return __builtin_amdgcn_perm(ub.u + 0x8000u, ua.u + 0x8000u, 0x07060302u);
}
__device__ __forceinline__ unsigned short f2bf_hu(float f) {
    union { float f; unsigned int u; } v; v.f = f;
    return (unsigned short)((v.u + 0x8000u) >> 16);
}
__device__ __forceinline__ float bfu(unsigned short u) {
    union { unsigned int u; float f; } v; v.u = ((unsigned int)u) << 16;
    return v.f;
}

// uniform idx-width check: lanes sample the first 64 high words of ei.
__device__ __forceinline__ int detect_is64(const void* ei, int t) {
    const unsigned int* ew = (const unsigned int*)ei;
    unsigned int hiw = ew[2 * (t & 63) + 1];
    return (__ballot(hiw != 0u) == 0ULL) ? 1 : 0;
}

// ws layout (bytes)
#define WS_BIAS_OFF 1024
#define WS_W1S_OFF  69632
#define WS_W2S_OFF  364544
#define WS_CNT_OFF  430080
#define WS_CUR_OFF  561152
#define WS_PERM_OFF 692224
#define WS_HBF_OFF  2790400
#define WS_HBF_END  (WS_HBF_OFF + N_NODES * NODE_DIM * 2)          // 11179008
#define WS_PS_OFF   WS_HBF_END
#define WS_PD_OFF   (WS_PS_OFF + N_NODES * 512 * 2)                // 44733440
#define WS_PD_END   (WS_PD_OFF + N_NODES * 512 * 2)                // 78287872

#define SEG_HIST 524288
#define SEG_W1S  147456
#define SEG_W2S  32768
#define SEG_BIAS 512
#define SEG_OUT  1073152
#define SEG_HBF  524288
#define PREP_TOT (SEG_HIST + SEG_W1S + SEG_W2S + SEG_BIAS + SEG_OUT + SEG_HBF)

// pp-mode W1s sublayout (shorts): [0,16384) part A = K=32 folded-t1 frags;
// [16384,81920) part B = rows 0..127 (psrc); [81920,147456) part C = rows 128..255 (pdst)
#define W1_PA 0
#define W1_PB 16384
#define W1_PC 81920

__device__ __forceinline__ float w1row(const float* Wn1, const float* Wc1, int k, int n) {
    return (n < 256) ? Wn1[k * 256 + n] : Wc1[k * 256 + (n - 256)];
}

// merged prep + hist: counts must be zeroed (hipMemsetAsync) before this kernel.
__global__ void prep_hist_kernel(const float* __restrict__ h, const float* __restrict__ x,
                                 const void* __restrict__ ei,
                                 const float* __restrict__ We2, const float* __restrict__ be2,
                                 const float* __restrict__ Wn1, const float* __restrict__ bn1,
                                 const float* __restrict__ Wn2,
                                 const float* __restrict__ Wc1, const float* __restrict__ bc1,
                                 float* __restrict__ out, float* __restrict__ biasC,
                                 unsigned short* __restrict__ W1s, unsigned short* __restrict__ W2s,
                                 int* __restrict__ counts, unsigned short* __restrict__ hbf,
                                 int use_pp) {
    int i = blockIdx.x * 256 + threadIdx.x;
    if (i < SEG_HIST) {
        int is64 = detect_is64(ei, threadIdx.x);
        int dst = is64 ? (int)((const long long*)ei)[N_EDGES + i]
                       : ((const int*)ei)[N_EDGES + i];
        atomicAdd(&counts[dst], 1);
        return;
    }
    i -= SEG_HIST;
    if (i < SEG_W1S) {
        if (use_pp) {
            if (i < W1_PB) {
                // part A: K=32, rows = folded edge-MLP layer 2 (orig rows 256..287)
                int jj = i & 7, ln = (i >> 3) & 63, rest = i >> 9;   // rest 0..31
                int step = rest & 1, tile = rest >> 1;
                int n = tile * 32 + (ln & 31);
                int j = step * 16 + ((ln >> 5) * 8) + jj;            // 0..31
                float s = 0.0f;
                #pragma unroll 8
                for (int q = 0; q < 32; ++q)
                    s += We2[j * 32 + q] * w1row(Wn1, Wc1, 256 + q, n);
                W1s[i] = f2bf_rne(s);
            } else if (i < W1_PC) {
                // part B: K=128, rows 0..127 (src half) for psrc node-GEMM
                int i2 = i - W1_PB;
                int jj = i2 & 7, ln = (i2 >> 3) & 63, rest = i2 >> 9; // 0..127
                int step = rest & 7, tile = rest >> 3;
                int n = tile * 32 + (ln & 31);
                int k = step * 16 + ((ln >> 5) * 8) + jj;
                W1s[i] = f2bf_rne(w1row(Wn1, Wc1, k, n));
            } else {
                // part C: K=128, rows 128..255 (dst half) for pdst node-GEMM
                int i2 = i - W1_PC;
                int jj = i2 & 7, ln = (i2 >> 3) & 63, rest = i2 >> 9;
                int step = rest & 7, tile = rest >> 3;
                int n = tile * 32 + (ln & 31);
                int k = 128 + step * 16 + ((ln >> 5) * 8) + jj;
                W1s[i] = f2bf_rne(w1row(Wn1, Wc1, k, n));
            }
        } else {
            // fallback layout: K=288, 18 steps; layer 2 folded for k >= 256
            int jj = i & 7, ln = (i >> 3) & 63, rest = i >> 9;
            int step = rest % 18, tile = rest / 18;
            int n = tile * 32 + (ln & 31);
            int k = step * 16 + ((ln >> 5) * 8) + jj;
            float v;
            if (k < 256) {
                v = w1row(Wn1, Wc1, k, n);
            } else {
                int j = k - 256;
                float s = 0.0f;
                #pragma unroll 8
                for (int q = 0; q < 32; ++q)
                    s += We2[j * 32 + q] * w1row(Wn1, Wc1, 256 + q, n);
                v = s;
            }
            W1s[i] = f2bf_rne(v);
        }
        return;
    }
    i -= SEG_W1S;
    if (i < SEG_W2S) {
        int jj = i & 7, ln = (i >> 3) & 63, rest = i >> 9;
        int step = rest & 15, tile = rest >> 4;
        int d = tile * 32 + (ln & 31);
        int k = step * 16 + ((ln >> 5) * 8) + jj;
        W2s[i] = f2bf_rne(Wn2[k * 128 + d]);
        return;
    }
    i -= SEG_W2S;
    if (i < SEG_BIAS) {
        int n = i;
        float s = (n < 256) ? bn1[n] : bc1[n - 256];
        #pragma unroll 8
        for (int q = 0; q < 32; ++q)
            s += be2[q] * w1row(Wn1, Wc1, 256 + q, n);
        biasC[n] = s;
        return;
    }
    i -= SEG_BIAS;
    if (i < SEG_OUT) {
        const int NH4 = N_NODES * NODE_DIM / 4;
        const float4* h4 = (const float4*)h;
        const float4* x4 = (const float4*)x;
        ((float4*)out)[i] = (i < NH4) ? h4[i] : x4[i - NH4];
        return;
    }
    i -= SEG_OUT;
    if (hbf != nullptr && i < SEG_HBF) {
        const float4* p = (const float4*)&h[i * 8];
        float4 v0 = p[0], v1 = p[1];
        uint4 o = make_uint4(pk_rne(v0.x, v0.y), pk_rne(v0.z, v0.w),
                             pk_rne(v1.x, v1.y), pk_rne(v1.z, v1.w));
        *(uint4*)&hbf[i * 8] = o;
    }
}

// fused scan: 128 blocks; each block redundantly computes all 128 chunk partials
__global__ __launch_bounds__(256)
void scan_fused_kernel(const int* __restrict__ counts, int* __restrict__ cursor) {
    __shared__ int pb[128];
    __shared__ int loc[256];
    const int t = threadIdx.x;
    const int b = blockIdx.x;
    if (t < 128) {
        const int4* c4 = (const int4*)(counts + t * 256);
        int s = 0;
        #pragma unroll 8
        for (int i = 0; i < 64; ++i) { int4 v = c4[i]; s += v.x + v.y + v.z + v.w; }
        pb[t] = s;
    }
    int c = counts[b * 256 + t];
    loc[t] = c;
    __syncthreads();
    if (t == 0) {
        int s = 0;
        for (int j = 0; j < 128; ++j) { int v = pb[j]; pb[j] = s; s += v; }
    }
    #pragma unroll
    for (int d = 1; d < 256; d <<= 1) {
        int v = (t >= d) ? loc[t - d] : 0;
        __syncthreads();
        loc[t] += v;
        __syncthreads();
    }
    cursor[b * 256 + t] = pb[b] + loc[t] - c;   // exclusive
}

__global__ void place_kernel(const void* __restrict__ ei,
                             int* __restrict__ cursor, int* __restrict__ perm) {
    int is64 = detect_is64(ei, threadIdx.x);
    int e = blockIdx.x * 256 + threadIdx.x;
    int dst = is64 ? (int)((const long long*)ei)[N_EDGES + e]
                   : ((const int*)ei)[N_EDGES + e];
    int pos = atomicAdd(&cursor[dst], 1);
    perm[pos] = e;
}

// node-term GEMMs: psrc[n] = h[n] @ W1rows[0:128]; pdst[n] = h[n] @ W1rows[128:256].
// 1024 blocks x 4 waves; wave = 4 n-tiles per pass; A read directly from hbf.
__global__ __launch_bounds__(256, 4)
void nterm_kernel(const unsigned short* __restrict__ hbf,
                  const unsigned short* __restrict__ W1s,
                  unsigned short* __restrict__ psrc,
                  unsigned short* __restrict__ pdst) {
    const int t = threadIdx.x;
    const int lane = t & 63;
    const int wv = t >> 6;
    const int lo = lane & 31;
    const int hi = lane >> 5;
    const int nb = blockIdx.x * 32;
    const int aoff = (nb + lo) * NODE_DIM + hi * 8;
    const int TSB = 8 * 64 * 8;          // 4096 shorts per n-tile

    for (int pass = 0; pass < 2; ++pass) {
        const unsigned short* WB = W1s + (pass ? W1_PC : W1_PB);
        unsigned short* outp = pass ? pdst : psrc;
        f32x16 a0, a1, a2, a3;
        #pragma unroll
        for (int r = 0; r < 16; ++r) { a0[r] = 0.f; a1[r] = 0.f; a2[r] = 0.f; a3[r] = 0.f; }
        const int b0 = (wv     ) * TSB + lane * 8;
        const int b1 = (wv +  4) * TSB + lane * 8;
        const int b2 = (wv +  8) * TSB + lane * 8;
        const int b3 = (wv + 12) * TSB + lane * 8;
        bf16x8 p0[2], p1[2], p2[2], p3[2];
        p0[0] = *(const bf16x8*)&WB[b0];
        p1[0] = *(const bf16x8*)&WB[b1];
        p2[0] = *(const bf16x8*)&WB[b2];
        p3[0] = *(const bf16x8*)&WB[b3];
        #pragma unroll
        for (int step = 0; step < 8; ++step) {
            const int cur = step & 1, nxt = cur ^ 1;
            if (step + 1 < 8) {
                p0[nxt] = *(const bf16x8*)&WB[b0 + (step + 1) * 512];
                p1[nxt] = *(const bf16x8*)&WB[b1 + (step + 1) * 512];
                p2[nxt] = *(const bf16x8*)&WB[b2 + (step + 1) * 512];
                p3[nxt] = *(const bf16x8*)&WB[b3 + (step + 1) * 512];
            }
            bf16x8 f = *(const bf16x8*)&hbf[aoff + step * 16];
            a0 = __builtin_amdgcn_mfma_f32_32x32x16_bf16(f, p0[cur], a0, 0, 0, 0);
            a1 = __builtin_amdgcn_mfma_f32_32x32x16_bf16(f, p1[cur], a1, 0, 0, 0);
            a2 = __builtin_amdgcn_mfma_f32_32x32x16_bf16(f, p2[cur], a2, 0, 0, 0);
            a3 = __builtin_amdgcn_mfma_f32_32x32x16_bf16(f, p3[cur], a3, 0, 0, 0);
        }
        #pragma unroll
        for (int r = 0; r < 16; ++r) {
            int er = (r & 3) + 8 * (r >> 2) + 4 * hi;
            unsigned short* row = &outp[(unsigned)(nb + er) * 512 + lo];
            row[(wv     ) * 32] = f2bf_rne(a0[r]);
            row[(wv +  4) * 32] = f2bf_rne(a1[r]);
            row[(wv +  8) * 32] = f2bf_rne(a2[r]);
            row[(wv + 12) * 32] = f2bf_rne(a3[r]);
        }
    }
}

// pp edge kernel v5: dual-buffer staging (psrc->smZs, pdst->smZd, SAME phase,
// pure uint4 copies -> zero staging VALU) + identity-B MFMA adds for both.
// LDS ~37 KB caps residency at 4 blocks/CU; launch_bounds(256,4) frees regalloc.
__global__ __launch_bounds__(256, 4)
void egnn_pp_kernel(const float* __restrict__ x,
                    const void* __restrict__ ei, const float* __restrict__ dist,
                    const float* __restrict__ We1, const float* __restrict__ be1,
                    const float* __restrict__ bn2, const float* __restrict__ Wc2,
                    const float* __restrict__ biasC,
                    const unsigned short* __restrict__ W1s,
                    const unsigned short* __restrict__ W2s,
                    const int* __restrict__ perm,
                    const unsigned short* __restrict__ psrc,
                    const unsigned short* __restrict__ pdst,
                    float* __restrict__ out)
{
    __shared__ unsigned short smZs[TE * SZ2];    // 16896 B; psrc slice / smH / smM alias
    __shared__ unsigned short smZd[TE * SZ2];    // 16896 B; pdst slice
    __shared__ unsigned short smT[TE * 40];      // 2560 B: t1 tile [32][32+pad]
    __shared__ int sidx[TE], didx[TE], eidx[TE];
    __shared__ float cw_s[TE];
    __shared__ float cxyz[3 * TE];

    unsigned short* smH = smZs;
    float* smM = (float*)smZs;

    const int t = threadIdx.x;           // 0..255
    const int lane = t & 63;
    const int wv = t >> 6;               // 0..3
    const int lo = lane & 31;
    const int hi = lane >> 5;
    const int swz = ((blockIdx.x & 7) * (NBLK / 8)) + (blockIdx.x >> 3);
    const int ebase = swz * TE;
    const int is64 = detect_is64(ei, t);

    // ---- 1. permuted edge indices + zero cw ----
    if (t < 2 * TE) {
        int e = t & (TE - 1);
        int eid = perm[ebase + e];
        int which = t >> 5;              // 0 = src, 1 = dst
        long long pos = (long long)which * N_EDGES + eid;
        int idx = is64 ? (int)((const long long*)ei)[pos] : ((const int*)ei)[pos];
        if (which == 0) { sidx[e] = idx; eidx[e] = eid; }
        else didx[e] = idx;
        if (t < TE) cw_s[t] = 0.0f;
    }
    __syncthreads();

    // ---- 2. t1 -> smT, unit dirs, stage coord cols (256..511) of BOTH tables ----
    {
        int e = t >> 3;                  // 0..31
        int j4 = (t & 7) * 4;
        float d = dist[eidx[e]];
        float s0 = silu_f(d * We1[j4 + 0] + be1[j4 + 0]);
        float s1 = silu_f(d * We1[j4 + 1] + be1[j4 + 1]);
        float s2 = silu_f(d * We1[j4 + 2] + be1[j4 + 2]);
        float s3 = silu_f(d * We1[j4 + 3] + be1[j4 + 3]);
        *(uint2*)&smT[e * 40 + j4] = make_uint2(pkbf(s0, s1), pkbf(s2, s3));
    }
    if (t < TE) {
        int s = sidx[t], dn = didx[t];
        float dx = x[s * 3 + 0] - x[dn * 3 + 0];
        float dy = x[s * 3 + 1] - x[dn * 3 + 1];
        float dz = x[s * 3 + 2] - x[dn * 3 + 2];
        float len = fmaxf(sqrtf(dx * dx + dy * dy + dz * dz), 1e-8f);
        float inv = 1.0f / len;
        cxyz[t] = dx * inv; cxyz[TE + t] = dy * inv; cxyz[2 * TE + t] = dz * inv;
    }
    #pragma unroll
    for (int it = 0; it < 4; ++it) {
        int id = it * 256 + t;
        int g = id & 31;                 // 8-col unit within 256
        int e = id >> 5;                 // 0..31
        uint4 a = *(const uint4*)&psrc[(unsigned)sidx[e] * 512 + 256 + g * 8];
        uint4 b = *(const uint4*)&pdst[(unsigned)didx[e] * 512 + 256 + g * 8];
        *(uint4*)&smZs[e * SZ2 + g * 8] = a;
        *(uint4*)&smZd[e * SZ2 + g * 8] = b;
    }
    __syncthreads();

    const int rowbase = 4 * hi;
    const int aT = lo * 40 + hi * 8;     // smT fragment base
    const int zb = lo * SZ2 + hi * 8;    // smZ fragment base (lane lo = edge row)

    // identity B-fragments: B_low[k][n]=d(k,n), B_high[k][n]=d(k,n-16)
    bf16x8 ilow, ihigh;
    #pragma unroll
    for (int ii = 0; ii < 8; ++ii) {
        int k = hi * 8 + ii;
        ilow[ii]  = (short)((k == lo)      ? 0x3F80 : 0);
        ihigh[ii] = (short)((k == lo - 16) ? 0x3F80 : 0);
    }

    bf16x8 a0T = *(const bf16x8*)&smT[aT];
    bf16x8 a1T = *(const bf16x8*)&smT[aT + 16];

    // ---- 3a. coord tiles (8+wv, 12+wv): mini-GEMM + identity Z-adds + c-reduce ----
    {
        const int c0off = wv * 32;
        const int c1off = (wv + 4) * 32;
        f32x16 c0, c1;
        {
            float b0 = biasC[256 + c0off + lo];
            float b1 = biasC[256 + c1off + lo];
            #pragma unroll
            for (int r = 0; r < 16; ++r) { c0[r] = b0; c1[r] = b1; }
        }
        const int tt0 = 8 + wv, tt1 = 12 + wv;
        bf16x8 w00 = *(const bf16x8*)&W1s[((tt0 * 2 + 0) * 64 + lane) * 8];
        bf16x8 w01 = *(const bf16x8*)&W1s[((tt0 * 2 + 1) * 64 + lane) * 8];
        bf16x8 w10 = *(const bf16x8*)&W1s[((tt1 * 2 + 0) * 64 + lane) * 8];
        bf16x8 w11 = *(const bf16x8*)&W1s[((tt1 * 2 + 1) * 64 + lane) * 8];
        c0 = __builtin_amdgcn_mfma_f32_32x32x16_bf16(a0T, w00, c0, 0, 0, 0);
        c0 = __builtin_amdgcn_mfma_f32_32x32x16_bf16(a1T, w01, c0, 0, 0, 0);
        c1 = __builtin_amdgcn_mfma_f32_32x32x16_bf16(a0T, w10, c1, 0, 0, 0);
        c1 = __builtin_amdgcn_mfma_f32_32x32x16_bf16(a1T, w11, c1, 0, 0, 0);
        bf16x8 zs00 = *(const bf16x8*)&smZs[zb + c0off];
        bf16x8 zs01 = *(const bf16x8*)&smZs[zb + c0off + 16];
        bf16x8 zs10 = *(const bf16x8*)&smZs[zb + c1off];
        bf16x8 zs11 = *(const bf16x8*)&smZs[zb + c1off + 16];
        c0 = __builtin_amdgcn_mfma_f32_32x32x16_bf16(zs00, ilow,  c0, 0, 0, 0);
        c0 = __builtin_amdgcn_mfma_f32_32x32x16_bf16(zs01, ihigh, c0, 0, 0, 0);
        c1 = __builtin_amdgcn_mfma_f32_32x32x16_bf16(zs10, ilow,  c1, 0, 0, 0);
        c1 = __builtin_amdgcn_mfma_f32_32x32x16_bf16(zs11, ihigh, c1, 0, 0, 0);
        bf16x8 zd00 = *(const bf16x8*)&smZd[zb + c0off];
        bf16x8 zd01 = *(const bf16x8*)&smZd[zb + c0off + 16];
        bf16x8 zd10 = *(const bf16x8*)&smZd[zb + c1off];
        bf16x8 zd11 = *(const bf16x8*)&smZd[zb + c1off + 16];
        c0 = __builtin_amdgcn_mfma_f32_32x32x16_bf16(zd00, ilow,  c0, 0, 0, 0);
        c0 = __builtin_amdgcn_mfma_f32_32x32x16_bf16(zd01, ihigh, c0, 0, 0, 0);
        c1 = __builtin_amdgcn_mfma_f32_32x32x16_bf16(zd10, ilow,  c1, 0, 0, 0);
        c1 = __builtin_amdgcn_mfma_f32_32x32x16_bf16(zd11, ihigh, c1, 0, 0, 0);
        float wc0 = Wc2[c0off + lo];
        float wc1 = Wc2[c1off + lo];
        float p[16];
        #pragma unroll
        for (int r = 0; r < 16; ++r)
            p[r] = silu_f(c0[r]) * wc0 + silu_f(c1[r]) * wc1;
        #pragma unroll
        for (int off = 1; off < 32; off <<= 1) {
            #pragma unroll
            for (int r = 0; r < 16; ++r) p[r] += __shfl_xor(p[r], off);
        }
        if (lo == 0) {
            #pragma unroll
            for (int r = 0; r < 16; ++r)
                atomicAdd(&cw_s[(r & 3) + 8 * (r >> 2) + rowbase], p[r]);
        }
    }
    __syncthreads();                     // coord frag reads done; cw atomics visible

    // ---- 4. stage node cols (0..255) of BOTH tables; scale cxyz by final cw ----
    #pragma unroll
    for (int it = 0; it < 4; ++it) {
        int id = it * 256 + t;
        int g = id & 31;
        int e = id >> 5;
        uint4 a = *(const uint4*)&psrc[(unsigned)sidx[e] * 512 + g * 8];
        uint4 b = *(const uint4*)&pdst[(unsigned)didx[e] * 512 + g * 8];
        *(uint4*)&smZs[e * SZ2 + g * 8] = a;
        *(uint4*)&smZd[e * SZ2 + g * 8] = b;
    }
    if (t < TE) {
        float w = cw_s[t];
        cxyz[t] *= w; cxyz[TE + t] *= w; cxyz[2 * TE + t] *= w;
    }
    __syncthreads();

    // ---- 5. node tiles (wv, wv+4): mini-GEMM + identity Z-adds ----
    f32x16 n0, n1;
    {
        const int n0off = wv * 32;
        const int n1off = (wv + 4) * 32;
        float b0 = biasC[n0off + lo];
        float b1 = biasC[n1off + lo];
        #pragma unroll
        for (int r = 0; r < 16; ++r) { n0[r] = b0; n1[r] = b1; }
        const int tt0 = wv, tt1 = wv + 4;
        bf16x8 w00 = *(const bf16x8*)&W1s[((tt0 * 2 + 0) * 64 + lane) * 8];
        bf16x8 w01 = *(const bf16x8*)&W1s[((tt0 * 2 + 1) * 64 + lane) * 8];
        bf16x8 w10 = *(const bf16x8*)&W1s[((tt1 * 2 + 0) * 64 + lane) * 8];
        bf16x8 w11 = *(const bf16x8*)&W1s[((tt1 * 2 + 1) * 64 + lane) * 8];
        n0 = __builtin_amdgcn_mfma_f32_32x32x16_bf16(a0T, w00, n0, 0, 0, 0);
        n0 = __builtin_amdgcn_mfma_f32_32x32x16_bf16(a1T, w01, n0, 0, 0, 0);
        n1 = __builtin_amdgcn_mfma_f32_32x32x16_bf16(a0T, w10, n1, 0, 0, 0);
        n1 = __builtin_amdgcn_mfma_f32_32x32x16_bf16(a1T, w11, n1, 0, 0, 0);
        bf16x8 zs00 = *(const bf16x8*)&smZs[zb + n0off];
        bf16x8 zs01 = *(const bf16x8*)&smZs[zb + n0off + 16];
        bf16x8 zs10 = *(const bf16x8*)&smZs[zb + n1off];
        bf16x8 zs11 = *(const bf16x8*)&smZs[zb + n1off + 16];
        n0 = __builtin_amdgcn_mfma_f32_32x32x16_bf16(zs00, ilow,  n0, 0, 0, 0);
        n0 = __builtin_amdgcn_mfma_f32_32x32x16_bf16(zs01, ihigh, n0, 0, 0, 0);
        n1 = __builtin_amdgcn_mfma_f32_32x32x16_bf16(zs10, ilow,  n1, 0, 0, 0);
        n1 = __builtin_amdgcn_mfma_f32_32x32x16_bf16(zs11, ihigh, n1, 0, 0, 0);
        bf16x8 zd00 = *(const bf16x8*)&smZd[zb + n0off];
        bf16x8 zd01 = *(const bf16x8*)&smZd[zb + n0off + 16];
        bf16x8 zd10 = *(const bf16x8*)&smZd[zb + n1off];
        bf16x8 zd11 = *(const bf16x8*)&smZd[zb + n1off + 16];
        n0 = __builtin_amdgcn_mfma_f32_32x32x16_bf16(zd00, ilow,  n0, 0, 0, 0);
        n0 = __builtin_amdgcn_mfma_f32_32x32x16_bf16(zd01, ihigh, n0, 0, 0, 0);
        n1 = __builtin_amdgcn_mfma_f32_32x32x16_bf16(zd10, ilow,  n1, 0, 0, 0);
        n1 = __builtin_amdgcn_mfma_f32_32x32x16_bf16(zd11, ihigh, n1, 0, 0, 0);
    }
    __syncthreads();                     // node frag reads done before in-place silu

    // silu -> smH (aliases smZs)
    #pragma unroll
    for (int r = 0; r < 16; ++r) {
        int er = (r & 3) + 8 * (r >> 2) + rowbase;
        smH[er * SZ2 + wv * 32 + lo]       = f2bf_hu(silu_f(n0[r]));
        smH[er * SZ2 + (wv + 4) * 32 + lo] = f2bf_hu(silu_f(n1[r]));
    }
    __syncthreads();                     // smH complete

    // ---- GEMM2: [32 x 256] @ [256 x 128]; wave = 1 d-tile; depth-2 prefetch ----
    {
        const int d = wv * 32 + lo;
        f32x16 acc;
        float bb = bn2[d];
        #pragma unroll
        for (int r = 0; r < 16; ++r) acc[r] = bb;
        const int hoff = lo * SZ2 + hi * 8;
        const int wb = wv * (16 * 64 * 8) + lane * 8;
        bf16x8 bs2[2];
        bs2[0] = *(const bf16x8*)&W2s[wb];
        #pragma unroll
        for (int step = 0; step < 16; ++step) {
            const int cur = step & 1, nxt = cur ^ 1;
            if (step + 1 < 16)
                bs2[nxt] = *(const bf16x8*)&W2s[wb + (step + 1) * 512];
            bf16x8 af = *(const bf16x8*)&smH[hoff + step * 16];
            acc = __builtin_amdgcn_mfma_f32_32x32x16_bf16(af, bs2[cur], acc, 0, 0, 0);
        }
        __syncthreads();                 // smH reads done before smM overwrite
        #pragma unroll
        for (int r = 0; r < 16; ++r) {
            int er = (r & 3) + 8 * (r >> 2) + rowbase;
            smM[er * MSTR + d] = acc[r];
        }
    }
    __syncthreads();

    // ---- run-reduction over sorted dst; interior RMW / boundary atomics ----
    {
        const int g = t >> 5;            // 8 edge-strided groups
        const int d4 = (t & 31) * 4;
        for (int e0 = g; e0 < TE; e0 += 8) {
            if (e0 > 0 && didx[e0] == didx[e0 - 1]) continue;
            float4 s = *(const float4*)&smM[e0 * MSTR + d4];
            int er = e0 + 1;
            while (er < TE && didx[er] == didx[e0]) {
                float4 v = *(const float4*)&smM[er * MSTR + d4];
                s.x += v.x; s.y += v.y; s.z += v.z; s.w += v.w;
                ++er;
            }
            float* dp = &out[didx[e0] * NODE_DIM + d4];
            if (e0 > 0 && er < TE) {
                float4 cur = *(const float4*)dp;
                cur.x += s.x; cur.y += s.y; cur.z += s.z; cur.w += s.w;
                *(float4*)dp = cur;
            } else {
                atomicAdd(dp + 0, s.x); atomicAdd(dp + 1, s.y);
                atomicAdd(dp + 2, s.z); atomicAdd(dp + 3, s.w);
            }
        }
    }
    if (t < TE) {
        int e0 = t;
        if (e0 == 0 || didx[e0] != didx[e0 - 1]) {
            float sx = cxyz[e0], sy = cxyz[TE + e0], sz = cxyz[2 * TE + e0];
            int er = e0 + 1;
            while (er < TE && didx[er] == didx[e0]) {
                sx += cxyz[er]; sy += cxyz[TE + er]; sz += cxyz[2 * TE + er];
                ++er;
            }
            float* xo = out + N_NODES * NODE_DIM + didx[e0] * 3;
            if (e0 > 0 && er < TE) {
                xo[0] += sx; xo[1] += sy; xo[2] += sz;
            } else {
                atomicAdd(xo + 0, sx); atomicAdd(xo + 1, sy); atomicAdd(xo + 2, sz);
            }
        }
    }
}

// fallback: R6 kernel (TE=32, split accumulator), used when ws can't host tables.
__global__ __launch_bounds__(256, 6)
void egnn_mfma_kernel(const float* __restrict__ h, const float* __restrict__ x,
                      const void* __restrict__ ei, const float* __restrict__ dist,
                      const float* __restrict__ We1, const float* __restrict__ be1,
                      const float* __restrict__ bn2, const float* __restrict__ Wc2,
                      const float* __restrict__ biasC,
                      const unsigned short* __restrict__ W1s,
                      const unsigned short* __restrict__ W2s,
                      const int* __restrict__ perm,
                      const unsigned short* __restrict__ hbf,
                      float* __restrict__ out)
{
    __shared__ unsigned short smA[TE * ASTR];
    __shared__ int sidx[TE], didx[TE], eidx[TE];
    __shared__ float cw_s[TE];
    __shared__ float cxyz[3 * TE];

    unsigned short* smH2 = smA;
    float* smM = (float*)smA;

    const int t = threadIdx.x;
    const int lane = t & 63;
    const int wv = t >> 6;
    const int lo = lane & 31;
    const int hi = lane >> 5;
    const int swz = ((blockIdx.x & 7) * (NBLK / 8)) + (blockIdx.x >> 3);
    const int ebase = swz * TE;
    const int is64 = detect_is64(ei, t);

    if (t < 2 * TE) {
        int e = t & (TE - 1);
        int eid = perm[ebase + e];
        int which = t >> 5;
        long long pos = (long long)which * N_EDGES + eid;
        int idx = is64 ? (int)((const long long*)ei)[pos] : ((const int*)ei)[pos];
        if (which == 0) { sidx[e] = idx; eidx[e] = eid; }
        else didx[e] = idx;
        if (t < TE) cw_s[t] = 0.0f;
    }
    __syncthreads();

    if (hbf != nullptr) {
        #pragma unroll
        for (int it = 0; it < 4; ++it) {
            int id = it * 256 + t;
            int g = id & 15;
            int half = (id >> 4) & 1;
            int e = id >> 5;
            int node = half ? didx[e] : sidx[e];
            uint4 v = *(const uint4*)&hbf[node * NODE_DIM + 8 * g];
            *(uint4*)&smA[e * ASTR + half * NODE_DIM + 8 * g] = v;
        }
    } else {
        #pragma unroll
        for (int it = 0; it < 4; ++it) {
            int id = it * 256 + t;
            int g8 = id & 15;
            int half = (id >> 4) & 1;
            int e = id >> 5;
            int node = half ? didx[e] : sidx[e];
            const float4* p = (const float4*)&h[node * NODE_DIM + 8 * g8];
            float4 v0 = p[0], v1 = p[1];
            unsigned int a0 = pkbf(v0.x, v0.y), a1 = pkbf(v0.z, v0.w);
            unsigned int a2 = pkbf(v1.x, v1.y), a3 = pkbf(v1.z, v1.w);
            *(uint4*)&smA[e * ASTR + half * NODE_DIM + 8 * g8] = make_uint4(a0, a1, a2, a3);
        }
    }
    {
        int e = t >> 3;
        int j4 = (t & 7) * 4;
        float d = dist[eidx[e]];
        float s0 = silu_f(d * We1[j4 + 0] + be1[j4 + 0]);
        float s1 = silu_f(d * We1[j4 + 1] + be1[j4 + 1]);
        float s2 = silu_f(d * We1[j4 + 2] + be1[j4 + 2]);
        float s3 = silu_f(d * We1[j4 + 3] + be1[j4 + 3]);
        *(uint2*)&smA[e * ASTR + 2 * NODE_DIM + j4] = make_uint2(pkbf(s0, s1), pkbf(s2, s3));
    }
    if (t < TE) {
        int s = sidx[t], dn = didx[t];
        float dx = x[s * 3 + 0] - x[dn * 3 + 0];
        float dy = x[s * 3 + 1] - x[dn * 3 + 1];
        float dz = x[s * 3 + 2] - x[dn * 3 + 2];
        float len = fmaxf(sqrtf(dx * dx + dy * dy + dz * dz), 1e-8f);
        float inv = 1.0f / len;
        cxyz[t] = dx * inv; cxyz[TE + t] = dy * inv; cxyz[2 * TE + t] = dz * inv;
    }
    __syncthreads();

    const int rowbase = 4 * hi;

    {
        f32x16 c0, c1;
        {
            float b0 = biasC[256 + wv * 32 + lo];
            float b1 = biasC[256 + (wv + 4) * 32 + lo];
            #pragma unroll
            for (int r = 0; r < 16; ++r) { c0[r] = b0; c1[r] = b1; }
        }
        {
            const int ao = lo * ASTR + hi * 8;
            const int TS = 18 * 64 * 8;
            const int q0 = (8 + wv) * TS + lane * 8;
            const int q1 = (12 + wv) * TS + lane * 8;
            bf16x8 p0[2], p1[2];
            p0[0] = *(const bf16x8*)&W1s[q0];
            p1[0] = *(const bf16x8*)&W1s[q1];
            #pragma unroll
            for (int step = 0; step < 18; ++step) {
                const int cur = step & 1, nxt = cur ^ 1;
                if (step + 1 < 18) {
                    p0[nxt] = *(const bf16x8*)&W1s[q0 + (step + 1) * 512];
                    p1[nxt] = *(const bf16x8*)&W1s[q1 + (step + 1) * 512];
                }
                bf16x8 f = *(const bf16x8*)&smA[ao + step * 16];
                c0 = __builtin_amdgcn_mfma_f32_32x32x16_bf16(f, p0[cur], c0, 0, 0, 0);
                c1 = __builtin_amdgcn_mfma_f32_32x32x16_bf16(f, p1[cur], c1, 0, 0, 0);
            }
        }
        float w0 = Wc2[wv * 32 + lo];
        float w1 = Wc2[(wv + 4) * 32 + lo];
        float p[16];
        #pragma unroll
        for (int r = 0; r < 16; ++r)
            p[r] = silu_f(c0[r]) * w0 + silu_f(c1[r]) * w1;
        #pragma unroll
        for (int off = 1; off < 32; off <<= 1) {
            #pragma unroll
            for (int r = 0; r < 16; ++r) p[r] += __shfl_xor(p[r], off);
        }
        if (lo == 0) {
            #pragma unroll
            for (int r = 0; r < 16; ++r)
                atomicAdd(&cw_s[(r & 3) + 8 * (r >> 2) + rowbase], p[r]);
        }
    }

    f32x16 a0, a1;
    {
        float b0 = biasC[wv * 32 + lo];
        float b1 = biasC[(wv + 4) * 32 + lo];
        #pragma unroll
        for (int r = 0; r < 16; ++r) { a0[r] = b0; a1[r] = b1; }
        const int ao = lo * ASTR + hi * 8;
        const int TS = 18 * 64 * 8;
        const int q0 = (wv) * TS + lane * 8;
        const int q1 = (wv + 4) * TS + lane * 8;
        bf16x8 p0[2], p1[2];
        p0[0] = *(const bf16x8*)&W1s[q0];
        p1[0] = *(const bf16x8*)&W1s[q1];
        #pragma unroll
        for (int step = 0; step < 18; ++step) {
            const int cur = step & 1, nxt = cur ^ 1;
            if (step + 1 < 18) {
                p0[nxt] = *(const bf16x8*)&W1s[q0 + (step + 1) * 512];
                p1[nxt] = *(const bf16x8*)&W1s[q1 + (step + 1) * 512];
            }
            bf16x8 f = *(const bf16x8*)&smA[ao + step * 16];
            a0 = __builtin_amdgcn_mfma_f32_32x32x16_bf16(f, p0[cur], a0, 0, 0, 0);
            a1 = __builtin_amdgcn_mfma_f32_32x32x16_bf16(f, p1[cur], a1, 0, 0, 0);
        }
    }
    __syncthreads();

    {
        const int jb0 = (wv    ) * 32 + lo;
        const int jb1 = (wv + 4) * 32 + lo;
        #pragma unroll
        for (int r = 0; r < 16; ++r) {
            int er = (r & 3) + 8 * (r >> 2) + rowbase;
            smH2[er * HSTR + jb0] = f2bf_hu(silu_f(a0[r]));
            smH2[er * HSTR + jb1] = f2bf_hu(silu_f(a1[r]));
        }
    }
    if (t < TE) {
        float w = cw_s[t];
        cxyz[t] *= w; cxyz[TE + t] *= w; cxyz[2 * TE + t] *= w;
    }
    __syncthreads();

    {
        const int d = wv * 32 + lo;
        f32x16 acc;
        float bb = bn2[d];
        #pragma unroll
        for (int r = 0; r < 16; ++r) acc[r] = bb;
        const int hoff = lo * HSTR + hi * 8;
        const int wb = wv * (16 * 64 * 8) + lane * 8;
        bf16x8 bs2[2];
        bs2[0] = *(const bf16x8*)&W2s[wb];
        #pragma unroll
        for (int step = 0; step < 16; ++step) {
            const int cur = step & 1, nxt = cur ^ 1;
            if (step + 1 < 16)
                bs2[nxt] = *(const bf16x8*)&W2s[wb + (step + 1) * 512];
            bf16x8 af = *(const bf16x8*)&smH2[hoff + step * 16];
            acc = __builtin_amdgcn_mfma_f32_32x32x16_bf16(af, bs2[cur], acc, 0, 0, 0);
        }
        __syncthreads();
        #pragma unroll
        for (int r = 0; r < 16; ++r) {
            int er = (r & 3) + 8 * (r >> 2) + rowbase;
            smM[er * MSTR + d] = acc[r];
        }
    }
    __syncthreads();

    {
        const int g = t >> 5;
        const int d4 = (t & 31) * 4;
        for (int e0 = g; e0 < TE; e0 += 8) {
            if (e0 > 0 && didx[e0] == didx[e0 - 1]) continue;
            float4 s = *(const float4*)&smM[e0 * MSTR + d4];
            int er = e0 + 1;
            while (er < TE && didx[er] == didx[e0]) {
                float4 v = *(const float4*)&smM[er * MSTR + d4];
                s.x += v.x; s.y += v.y; s.z += v.z; s.w += v.w;
                ++er;
            }
            float* dp = &out[didx[e0] * NODE_DIM + d4];
            if (e0 > 0 && er < TE) {
                float4 cur = *(const float4*)dp;
                cur.x += s.x; cur.y += s.y; cur.z += s.z; cur.w += s.w;
                *(float4*)dp = cur;
            } else {
                atomicAdd(dp + 0, s.x); atomicAdd(dp + 1, s.y);
                atomicAdd(dp + 2, s.z); atomicAdd(dp + 3, s.w);
            }
        }
    }
    if (t < TE) {
        int e0 = t;
        if (e0 == 0 || didx[e0] != didx[e0 - 1]) {
            float sx = cxyz[e0], sy = cxyz[TE + e0], sz = cxyz[2 * TE + e0];
            int er = e0 + 1;
            while (er < TE && didx[er] == didx[e0]) {
                sx += cxyz[er]; sy += cxyz[TE + er]; sz += cxyz[2 * TE + er];
                ++er;
            }
            float* xo = out + N_NODES * NODE_DIM + didx[e0] * 3;
            if (e0 > 0 && er < TE) {
                xo[0] += sx; xo[1] += sy; xo[2] += sz;
            } else {
                atomicAdd(xo + 0, sx); atomicAdd(xo + 1, sy); atomicAdd(xo + 2, sz);
            }
        }
    }
}

extern "C" void kernel_launch(void* const* d_in, const int* in_sizes, int n_in,
                              void* d_out, int out_size, void* d_ws, size_t ws_size,
                              hipStream_t stream) {
    const float* h    = (const float*)d_in[0];
    const float* x    = (const float*)d_in[1];
    const void*  ei   = d_in[2];
    const float* dist = (const float*)d_in[3];
    const float* We1  = (const float*)d_in[4];
    const float* be1  = (const float*)d_in[5];
    const float* We2  = (const float*)d_in[6];
    const float* be2  = (const float*)d_in[7];
    const float* Wn1  = (const float*)d_in[8];
    const float* bn1  = (const float*)d_in[9];
    const float* Wn2  = (const float*)d_in[10];
    const float* bn2  = (const float*)d_in[11];
    const float* Wc1  = (const float*)d_in[12];
    const float* bc1  = (const float*)d_in[13];
    const float* Wc2  = (const float*)d_in[14];
    float* out = (float*)d_out;

    float* biasC = (float*)((char*)d_ws + WS_BIAS_OFF);
    unsigned short* W1s = (unsigned short*)((char*)d_ws + WS_W1S_OFF);
    unsigned short* W2s = (unsigned short*)((char*)d_ws + WS_W2S_OFF);
    int* counts   = (int*)((char*)d_ws + WS_CNT_OFF);
    int* cursor   = (int*)((char*)d_ws + WS_CUR_OFF);
    int* perm     = (int*)((char*)d_ws + WS_PERM_OFF);
    unsigned short* hbf = (ws_size >= (size_t)WS_HBF_END)
                        ? (unsigned short*)((char*)d_ws + WS_HBF_OFF) : nullptr;
    int use_pp = (ws_size >= (size_t)WS_PD_END && hbf != nullptr) ? 1 : 0;
    unsigned short* psrc = use_pp ? (unsigned short*)((char*)d_ws + WS_PS_OFF) : nullptr;
    unsigned short* pdst = use_pp ? (unsigned short*)((char*)d_ws + WS_PD_OFF) : nullptr;

    hipMemsetAsync(counts, 0, N_NODES * sizeof(int), stream);

    prep_hist_kernel<<<PREP_TOT / 256, 256, 0, stream>>>(
        h, x, ei, We2, be2, Wn1, bn1, Wn2, Wc1, bc1,
        out, biasC, W1s, W2s, counts, hbf, use_pp);

    scan_fused_kernel<<<128, 256, 0, stream>>>(counts, cursor);
    place_kernel<<<N_EDGES / 256, 256, 0, stream>>>(ei, cursor, perm);

    if (use_pp) {
        nterm_kernel<<<N_NODES / 32, 256, 0, stream>>>(hbf, W1s, psrc, pdst);
        egnn_pp_kernel<<<NBLK, 256, 0, stream>>>(
            x, ei, dist, We1, be1, bn2, Wc2, biasC, W1s, W2s, perm, psrc, pdst, out);
    } else {
        egnn_mfma_kernel<<<NBLK, 256, 0, stream>>>(
            h, x, ei, dist, We1, be1, bn2, Wc2, biasC, W1s, W2s, perm, hbf, out);
    }
}

// Round 13
// 435.599 us; speedup vs baseline: 1.0245x; 1.0245x over previous
//
#include <hip/hip_runtime.h>
#include <math.h>

#define N_NODES 32768
#define N_EDGES 524288
#define NODE_DIM 128
#define HIDDEN 256
#define EDGE_DIM 32
#define TE 32              // edges per block
#define NBLK (N_EDGES / TE)
#define ASTR 296           // fallback smA row stride (bf16)
#define HSTR 264           // fallback smH row stride (bf16)
#define SZ2  264           // pp smZ/smH row stride (bf16): 528 B, 16B-aligned
#define MSTR 132           // smM row stride (f32): 528 B, 16B-aligned

typedef __attribute__((ext_vector_type(8))) short bf16x8;
typedef __attribute__((ext_vector_type(16))) float f32x16;

__device__ __forceinline__ float silu_f(float v) {
    float e = __expf(-v);
    return v * __builtin_amdgcn_rcpf(1.0f + e);
}

__device__ __forceinline__ unsigned short f2bf_rne(float f) {
    union { float f; unsigned int u; } v; v.f = f;
    return (unsigned short)((v.u + 0x7fffu + ((v.u >> 16) & 1u)) >> 16);
}
__device__ __forceinline__ unsigned int pk_rne(float a, float b) {
    return (unsigned int)f2bf_rne(a) | ((unsigned int)f2bf_rne(b) << 16);
}
// half-up pack of two floats -> (bf16(a) | bf16(b)<<16)
__device__ __forceinline__ unsigned int pkbf(float a, float b) {
    union { float f; unsigned int u; } ua, ub; ua.f = a; ub.f = b;
    return __builtin_amdgcn_perm(ub.u + 0x8000u, ua.u + 0x8000u, 0x07060302u);
}
__device__ __forceinline__ unsigned short f2bf_hu(float f) {
    union { float f; unsigned int u; } v; v.f = f;
    return (unsigned short)((v.u + 0x8000u) >> 16);
}
__device__ __forceinline__ float bfu(unsigned short u) {
    union { unsigned int u; float f; } v; v.u = ((unsigned int)u) << 16;
    return v.f;
}
// packed bf16x2 + bf16x2 -> bf16x2 (f32 math, half-up repack)
__device__ __forceinline__ unsigned int addbf2(unsigned int a, unsigned int b) {
    float l = __uint_as_float(a << 16) + __uint_as_float(b << 16);
    float h = __uint_as_float(a & 0xffff0000u) + __uint_as_float(b & 0xffff0000u);
    return pkbf(l, h);
}

// uniform idx-width check: lanes sample the first 64 high words of ei.
__device__ __forceinline__ int detect_is64(const void* ei, int t) {
    const unsigned int* ew = (const unsigned int*)ei;
    unsigned int hiw = ew[2 * (t & 63) + 1];
    return (__ballot(hiw != 0u) == 0ULL) ? 1 : 0;
}

// ws layout (bytes)
#define WS_BIAS_OFF 1024
#define WS_W1S_OFF  69632
#define WS_W2S_OFF  364544
#define WS_CNT_OFF  430080
#define WS_CUR_OFF  561152
#define WS_PERM_OFF 692224
#define WS_HBF_OFF  2790400
#define WS_HBF_END  (WS_HBF_OFF + N_NODES * NODE_DIM * 2)          // 11179008
#define WS_PS_OFF   WS_HBF_END
#define WS_PD_OFF   (WS_PS_OFF + N_NODES * 512 * 2)                // 44733440
#define WS_PD_END   (WS_PD_OFF + N_NODES * 512 * 2)                // 78287872

#define SEG_HIST 524288
#define SEG_W1S  147456
#define SEG_W2S  32768
#define SEG_BIAS 512
#define SEG_OUT  1073152
#define SEG_HBF  524288
#define PREP_TOT (SEG_HIST + SEG_W1S + SEG_W2S + SEG_BIAS + SEG_OUT + SEG_HBF)

// pp-mode W1s sublayout (shorts): [0,16384) part A = K=32 folded-t1 frags;
// [16384,81920) part B = rows 0..127 (psrc); [81920,147456) part C = rows 128..255 (pdst)
#define W1_PA 0
#define W1_PB 16384
#define W1_PC 81920

// merged place+nterm grid split
#define PLACE_BLKS (N_EDGES / 256)     // 2048
#define NT_BLKS    (N_NODES / 32)      // 1024

__device__ __forceinline__ float w1row(const float* Wn1, const float* Wc1, int k, int n) {
    return (n < 256) ? Wn1[k * 256 + n] : Wc1[k * 256 + (n - 256)];
}

// merged prep + hist: counts must be zeroed (hipMemsetAsync) before this kernel.
__global__ void prep_hist_kernel(const float* __restrict__ h, const float* __restrict__ x,
                                 const void* __restrict__ ei,
                                 const float* __restrict__ We2, const float* __restrict__ be2,
                                 const float* __restrict__ Wn1, const float* __restrict__ bn1,
                                 const float* __restrict__ Wn2,
                                 const float* __restrict__ Wc1, const float* __restrict__ bc1,
                                 float* __restrict__ out, float* __restrict__ biasC,
                                 unsigned short* __restrict__ W1s, unsigned short* __restrict__ W2s,
                                 int* __restrict__ counts, unsigned short* __restrict__ hbf,
                                 int use_pp) {
    int i = blockIdx.x * 256 + threadIdx.x;
    if (i < SEG_HIST) {
        int is64 = detect_is64(ei, threadIdx.x);
        int dst = is64 ? (int)((const long long*)ei)[N_EDGES + i]
                       : ((const int*)ei)[N_EDGES + i];
        atomicAdd(&counts[dst], 1);
        return;
    }
    i -= SEG_HIST;
    if (i < SEG_W1S) {
        if (use_pp) {
            if (i < W1_PB) {
                // part A: K=32, rows = folded edge-MLP layer 2 (orig rows 256..287)
                int jj = i & 7, ln = (i >> 3) & 63, rest = i >> 9;   // rest 0..31
                int step = rest & 1, tile = rest >> 1;
                int n = tile * 32 + (ln & 31);
                int j = step * 16 + ((ln >> 5) * 8) + jj;            // 0..31
                float s = 0.0f;
                #pragma unroll 8
                for (int q = 0; q < 32; ++q)
                    s += We2[j * 32 + q] * w1row(Wn1, Wc1, 256 + q, n);
                W1s[i] = f2bf_rne(s);
            } else if (i < W1_PC) {
                // part B: K=128, rows 0..127 (src half) for psrc node-GEMM
                int i2 = i - W1_PB;
                int jj = i2 & 7, ln = (i2 >> 3) & 63, rest = i2 >> 9; // 0..127
                int step = rest & 7, tile = rest >> 3;
                int n = tile * 32 + (ln & 31);
                int k = step * 16 + ((ln >> 5) * 8) + jj;
                W1s[i] = f2bf_rne(w1row(Wn1, Wc1, k, n));
            } else {
                // part C: K=128, rows 128..255 (dst half) for pdst node-GEMM
                int i2 = i - W1_PC;
                int jj = i2 & 7, ln = (i2 >> 3) & 63, rest = i2 >> 9;
                int step = rest & 7, tile = rest >> 3;
                int n = tile * 32 + (ln & 31);
                int k = 128 + step * 16 + ((ln >> 5) * 8) + jj;
                W1s[i] = f2bf_rne(w1row(Wn1, Wc1, k, n));
            }
        } else {
            // fallback layout: K=288, 18 steps; layer 2 folded for k >= 256
            int jj = i & 7, ln = (i >> 3) & 63, rest = i >> 9;
            int step = rest % 18, tile = rest / 18;
            int n = tile * 32 + (ln & 31);
            int k = step * 16 + ((ln >> 5) * 8) + jj;
            float v;
            if (k < 256) {
                v = w1row(Wn1, Wc1, k, n);
            } else {
                int j = k - 256;
                float s = 0.0f;
                #pragma unroll 8
                for (int q = 0; q < 32; ++q)
                    s += We2[j * 32 + q] * w1row(Wn1, Wc1, 256 + q, n);
                v = s;
            }
            W1s[i] = f2bf_rne(v);
        }
        return;
    }
    i -= SEG_W1S;
    if (i < SEG_W2S) {
        int jj = i & 7, ln = (i >> 3) & 63, rest = i >> 9;
        int step = rest & 15, tile = rest >> 4;
        int d = tile * 32 + (ln & 31);
        int k = step * 16 + ((ln >> 5) * 8) + jj;
        W2s[i] = f2bf_rne(Wn2[k * 128 + d]);
        return;
    }
    i -= SEG_W2S;
    if (i < SEG_BIAS) {
        int n = i;
        float s = (n < 256) ? bn1[n] : bc1[n - 256];
        #pragma unroll 8
        for (int q = 0; q < 32; ++q)
            s += be2[q] * w1row(Wn1, Wc1, 256 + q, n);
        biasC[n] = s;
        return;
    }
    i -= SEG_BIAS;
    if (i < SEG_OUT) {
        const int NH4 = N_NODES * NODE_DIM / 4;
        const float4* h4 = (const float4*)h;
        const float4* x4 = (const float4*)x;
        ((float4*)out)[i] = (i < NH4) ? h4[i] : x4[i - NH4];
        return;
    }
    i -= SEG_OUT;
    if (hbf != nullptr && i < SEG_HBF) {
        const float4* p = (const float4*)&h[i * 8];
        float4 v0 = p[0], v1 = p[1];
        uint4 o = make_uint4(pk_rne(v0.x, v0.y), pk_rne(v0.z, v0.w),
                             pk_rne(v1.x, v1.y), pk_rne(v1.z, v1.w));
        *(uint4*)&hbf[i * 8] = o;
    }
}

// fused scan: 128 blocks; each block redundantly computes all 128 chunk partials
__global__ __launch_bounds__(256)
void scan_fused_kernel(const int* __restrict__ counts, int* __restrict__ cursor) {
    __shared__ int pb[128];
    __shared__ int loc[256];
    const int t = threadIdx.x;
    const int b = blockIdx.x;
    if (t < 128) {
        const int4* c4 = (const int4*)(counts + t * 256);
        int s = 0;
        #pragma unroll 8
        for (int i = 0; i < 64; ++i) { int4 v = c4[i]; s += v.x + v.y + v.z + v.w; }
        pb[t] = s;
    }
    int c = counts[b * 256 + t];
    loc[t] = c;
    __syncthreads();
    if (t == 0) {
        int s = 0;
        for (int j = 0; j < 128; ++j) { int v = pb[j]; pb[j] = s; s += v; }
    }
    #pragma unroll
    for (int d = 1; d < 256; d <<= 1) {
        int v = (t >= d) ? loc[t - d] : 0;
        __syncthreads();
        loc[t] += v;
        __syncthreads();
    }
    cursor[b * 256 + t] = pb[b] + loc[t] - c;   // exclusive
}

// merged place + nterm: blocks [0,PLACE_BLKS) scatter edge ids into perm;
// blocks [PLACE_BLKS, PLACE_BLKS+NT_BLKS) compute psrc/pdst node-GEMMs.
// Independent work -> overlaps on the machine, one launch gap removed.
__global__ __launch_bounds__(256, 4)
void place_nterm_kernel(const void* __restrict__ ei,
                        int* __restrict__ cursor, int* __restrict__ perm,
                        const unsigned short* __restrict__ hbf,
                        const unsigned short* __restrict__ W1s,
                        unsigned short* __restrict__ psrc,
                        unsigned short* __restrict__ pdst) {
    if (blockIdx.x < PLACE_BLKS) {
        int is64 = detect_is64(ei, threadIdx.x);
        int e = blockIdx.x * 256 + threadIdx.x;
        int dst = is64 ? (int)((const long long*)ei)[N_EDGES + e]
                       : ((const int*)ei)[N_EDGES + e];
        int pos = atomicAdd(&cursor[dst], 1);
        perm[pos] = e;
        return;
    }
    // nterm role
    const int t = threadIdx.x;
    const int lane = t & 63;
    const int wv = t >> 6;
    const int lo = lane & 31;
    const int hi = lane >> 5;
    const int nb = (blockIdx.x - PLACE_BLKS) * 32;
    const int aoff = (nb + lo) * NODE_DIM + hi * 8;
    const int TSB = 8 * 64 * 8;          // 4096 shorts per n-tile

    for (int pass = 0; pass < 2; ++pass) {
        const unsigned short* WB = W1s + (pass ? W1_PC : W1_PB);
        unsigned short* outp = pass ? pdst : psrc;
        f32x16 a0, a1, a2, a3;
        #pragma unroll
        for (int r = 0; r < 16; ++r) { a0[r] = 0.f; a1[r] = 0.f; a2[r] = 0.f; a3[r] = 0.f; }
        const int b0 = (wv     ) * TSB + lane * 8;
        const int b1 = (wv +  4) * TSB + lane * 8;
        const int b2 = (wv +  8) * TSB + lane * 8;
        const int b3 = (wv + 12) * TSB + lane * 8;
        bf16x8 p0[2], p1[2], p2[2], p3[2];
        p0[0] = *(const bf16x8*)&WB[b0];
        p1[0] = *(const bf16x8*)&WB[b1];
        p2[0] = *(const bf16x8*)&WB[b2];
        p3[0] = *(const bf16x8*)&WB[b3];
        #pragma unroll
        for (int step = 0; step < 8; ++step) {
            const int cur = step & 1, nxt = cur ^ 1;
            if (step + 1 < 8) {
                p0[nxt] = *(const bf16x8*)&WB[b0 + (step + 1) * 512];
                p1[nxt] = *(const bf16x8*)&WB[b1 + (step + 1) * 512];
                p2[nxt] = *(const bf16x8*)&WB[b2 + (step + 1) * 512];
                p3[nxt] = *(const bf16x8*)&WB[b3 + (step + 1) * 512];
            }
            bf16x8 f = *(const bf16x8*)&hbf[aoff + step * 16];
            a0 = __builtin_amdgcn_mfma_f32_32x32x16_bf16(f, p0[cur], a0, 0, 0, 0);
            a1 = __builtin_amdgcn_mfma_f32_32x32x16_bf16(f, p1[cur], a1, 0, 0, 0);
            a2 = __builtin_amdgcn_mfma_f32_32x32x16_bf16(f, p2[cur], a2, 0, 0, 0);
            a3 = __builtin_amdgcn_mfma_f32_32x32x16_bf16(f, p3[cur], a3, 0, 0, 0);
        }
        #pragma unroll
        for (int r = 0; r < 16; ++r) {
            int er = (r & 3) + 8 * (r >> 2) + 4 * hi;
            unsigned short* row = &outp[(unsigned)(nb + er) * 512 + lo];
            row[(wv     ) * 32] = f2bf_rne(a0[r]);
            row[(wv +  4) * 32] = f2bf_rne(a1[r]);
            row[(wv +  8) * 32] = f2bf_rne(a2[r]);
            row[(wv + 12) * 32] = f2bf_rne(a3[r]);
        }
    }
}

// standalone place (non-pp fallback path)
__global__ void place_kernel(const void* __restrict__ ei,
                             int* __restrict__ cursor, int* __restrict__ perm) {
    int is64 = detect_is64(ei, threadIdx.x);
    int e = blockIdx.x * 256 + threadIdx.x;
    int dst = is64 ? (int)((const long long*)ei)[N_EDGES + e]
                   : ((const int*)ei)[N_EDGES + e];
    int pos = atomicAdd(&cursor[dst], 1);
    perm[pos] = e;
}

// pp edge kernel v4 (R11 structure, launch_bounds 7): fused addbf2 staging +
// identity-B MFMA adds reading smZ vector fragments. 72 regs/wave -> 7 waves/SIMD.
__global__ __launch_bounds__(256, 7)
void egnn_pp_kernel(const float* __restrict__ x,
                    const void* __restrict__ ei, const float* __restrict__ dist,
                    const float* __restrict__ We1, const float* __restrict__ be1,
                    const float* __restrict__ bn2, const float* __restrict__ Wc2,
                    const float* __restrict__ biasC,
                    const unsigned short* __restrict__ W1s,
                    const unsigned short* __restrict__ W2s,
                    const int* __restrict__ perm,
                    const unsigned short* __restrict__ psrc,
                    const unsigned short* __restrict__ pdst,
                    float* __restrict__ out)
{
    __shared__ unsigned short smZ[TE * SZ2];     // 16896 B; staging / smH / smM alias
    __shared__ unsigned short smT[TE * 40];      // 2560 B: t1 tile [32][32+pad]
    __shared__ int sidx[TE], didx[TE], eidx[TE];
    __shared__ float cw_s[TE];
    __shared__ float cxyz[3 * TE];

    unsigned short* smH = smZ;
    float* smM = (float*)smZ;

    const int t = threadIdx.x;           // 0..255
    const int lane = t & 63;
    const int wv = t >> 6;               // 0..3
    const int lo = lane & 31;
    const int hi = lane >> 5;
    const int swz = ((blockIdx.x & 7) * (NBLK / 8)) + (blockIdx.x >> 3);
    const int ebase = swz * TE;
    const int is64 = detect_is64(ei, t);

    // ---- 1. permuted edge indices + zero cw ----
    if (t < 2 * TE) {
        int e = t & (TE - 1);
        int eid = perm[ebase + e];
        int which = t >> 5;              // 0 = src, 1 = dst
        long long pos = (long long)which * N_EDGES + eid;
        int idx = is64 ? (int)((const long long*)ei)[pos] : ((const int*)ei)[pos];
        if (which == 0) { sidx[e] = idx; eidx[e] = eid; }
        else didx[e] = idx;
        if (t < TE) cw_s[t] = 0.0f;
    }
    __syncthreads();

    // ---- 2. t1 -> smT, unit dirs, stage summed coord cols (256..511) ----
    {
        int e = t >> 3;                  // 0..31
        int j4 = (t & 7) * 4;
        float d = dist[eidx[e]];
        float s0 = silu_f(d * We1[j4 + 0] + be1[j4 + 0]);
        float s1 = silu_f(d * We1[j4 + 1] + be1[j4 + 1]);
        float s2 = silu_f(d * We1[j4 + 2] + be1[j4 + 2]);
        float s3 = silu_f(d * We1[j4 + 3] + be1[j4 + 3]);
        *(uint2*)&smT[e * 40 + j4] = make_uint2(pkbf(s0, s1), pkbf(s2, s3));
    }
    if (t < TE) {
        int s = sidx[t], dn = didx[t];
        float dx = x[s * 3 + 0] - x[dn * 3 + 0];
        float dy = x[s * 3 + 1] - x[dn * 3 + 1];
        float dz = x[s * 3 + 2] - x[dn * 3 + 2];
        float len = fmaxf(sqrtf(dx * dx + dy * dy + dz * dz), 1e-8f);
        float inv = 1.0f / len;
        cxyz[t] = dx * inv; cxyz[TE + t] = dy * inv; cxyz[2 * TE + t] = dz * inv;
    }
    #pragma unroll
    for (int it = 0; it < 4; ++it) {
        int id = it * 256 + t;
        int g = id & 31;                 // 8-col unit within 256
        int e = id >> 5;                 // 0..31
        uint4 a = *(const uint4*)&psrc[(unsigned)sidx[e] * 512 + 256 + g * 8];
        uint4 b = *(const uint4*)&pdst[(unsigned)didx[e] * 512 + 256 + g * 8];
        uint4 o = make_uint4(addbf2(a.x, b.x), addbf2(a.y, b.y),
                             addbf2(a.z, b.z), addbf2(a.w, b.w));
        *(uint4*)&smZ[e * SZ2 + g * 8] = o;
    }
    __syncthreads();

    const int rowbase = 4 * hi;
    const int aT = lo * 40 + hi * 8;     // smT fragment base
    const int zb = lo * SZ2 + hi * 8;    // smZ fragment base (lane lo = edge row)

    // identity B-fragments: B_low[k][n]=d(k,n), B_high[k][n]=d(k,n-16)
    bf16x8 ilow, ihigh;
    #pragma unroll
    for (int ii = 0; ii < 8; ++ii) {
        int k = hi * 8 + ii;
        ilow[ii]  = (short)((k == lo)      ? 0x3F80 : 0);
        ihigh[ii] = (short)((k == lo - 16) ? 0x3F80 : 0);
    }

    bf16x8 a0T = *(const bf16x8*)&smT[aT];
    bf16x8 a1T = *(const bf16x8*)&smT[aT + 16];

    // ---- 3a. coord tiles (8+wv, 12+wv): mini-GEMM + identity Z-adds + c-reduce ----
    {
        const int c0off = wv * 32;
        const int c1off = (wv + 4) * 32;
        f32x16 c0, c1;
        {
            float b0 = biasC[256 + c0off + lo];
            float b1 = biasC[256 + c1off + lo];
            #pragma unroll
            for (int r = 0; r < 16; ++r) { c0[r] = b0; c1[r] = b1; }
        }
        const int tt0 = 8 + wv, tt1 = 12 + wv;
        bf16x8 w00 = *(const bf16x8*)&W1s[((tt0 * 2 + 0) * 64 + lane) * 8];
        bf16x8 w01 = *(const bf16x8*)&W1s[((tt0 * 2 + 1) * 64 + lane) * 8];
        bf16x8 w10 = *(const bf16x8*)&W1s[((tt1 * 2 + 0) * 64 + lane) * 8];
        bf16x8 w11 = *(const bf16x8*)&W1s[((tt1 * 2 + 1) * 64 + lane) * 8];
        c0 = __builtin_amdgcn_mfma_f32_32x32x16_bf16(a0T, w00, c0, 0, 0, 0);
        c0 = __builtin_amdgcn_mfma_f32_32x32x16_bf16(a1T, w01, c0, 0, 0, 0);
        c1 = __builtin_amdgcn_mfma_f32_32x32x16_bf16(a0T, w10, c1, 0, 0, 0);
        c1 = __builtin_amdgcn_mfma_f32_32x32x16_bf16(a1T, w11, c1, 0, 0, 0);
        bf16x8 z00 = *(const bf16x8*)&smZ[zb + c0off];
        bf16x8 z01 = *(const bf16x8*)&smZ[zb + c0off + 16];
        bf16x8 z10 = *(const bf16x8*)&smZ[zb + c1off];
        bf16x8 z11 = *(const bf16x8*)&smZ[zb + c1off + 16];
        c0 = __builtin_amdgcn_mfma_f32_32x32x16_bf16(z00, ilow,  c0, 0, 0, 0);
        c0 = __builtin_amdgcn_mfma_f32_32x32x16_bf16(z01, ihigh, c0, 0, 0, 0);
        c1 = __builtin_amdgcn_mfma_f32_32x32x16_bf16(z10, ilow,  c1, 0, 0, 0);
        c1 = __builtin_amdgcn_mfma_f32_32x32x16_bf16(z11, ihigh, c1, 0, 0, 0);
        float wc0 = Wc2[c0off + lo];
        float wc1 = Wc2[c1off + lo];
        float p[16];
        #pragma unroll
        for (int r = 0; r < 16; ++r)
            p[r] = silu_f(c0[r]) * wc0 + silu_f(c1[r]) * wc1;
        #pragma unroll
        for (int off = 1; off < 32; off <<= 1) {
            #pragma unroll
            for (int r = 0; r < 16; ++r) p[r] += __shfl_xor(p[r], off);
        }
        if (lo == 0) {
            #pragma unroll
            for (int r = 0; r < 16; ++r)
                atomicAdd(&cw_s[(r & 3) + 8 * (r >> 2) + rowbase], p[r]);
        }
    }
    __syncthreads();                     // smZ coord frag reads done; cw atomics visible

    // ---- 4. stage summed node cols (0..255); scale cxyz by final cw ----
    #pragma unroll
    for (int it = 0; it < 4; ++it) {
        int id = it * 256 + t;
        int g = id & 31;
        int e = id >> 5;
        uint4 a = *(const uint4*)&psrc[(unsigned)sidx[e] * 512 + g * 8];
        uint4 b = *(const uint4*)&pdst[(unsigned)didx[e] * 512 + g * 8];
        uint4 o = make_uint4(addbf2(a.x, b.x), addbf2(a.y, b.y),
                             addbf2(a.z, b.z), addbf2(a.w, b.w));
        *(uint4*)&smZ[e * SZ2 + g * 8] = o;
    }
    if (t < TE) {
        float w = cw_s[t];
        cxyz[t] *= w; cxyz[TE + t] *= w; cxyz[2 * TE + t] *= w;
    }
    __syncthreads();

    // ---- 5. node tiles (wv, wv+4): mini-GEMM + identity Z-adds ----
    f32x16 n0, n1;
    {
        const int n0off = wv * 32;
        const int n1off = (wv + 4) * 32;
        float b0 = biasC[n0off + lo];
        float b1 = biasC[n1off + lo];
        #pragma unroll
        for (int r = 0; r < 16; ++r) { n0[r] = b0; n1[r] = b1; }
        const int tt0 = wv, tt1 = wv + 4;
        bf16x8 w00 = *(const bf16x8*)&W1s[((tt0 * 2 + 0) * 64 + lane) * 8];
        bf16x8 w01 = *(const bf16x8*)&W1s[((tt0 * 2 + 1) * 64 + lane) * 8];
        bf16x8 w10 = *(const bf16x8*)&W1s[((tt1 * 2 + 0) * 64 + lane) * 8];
        bf16x8 w11 = *(const bf16x8*)&W1s[((tt1 * 2 + 1) * 64 + lane) * 8];
        n0 = __builtin_amdgcn_mfma_f32_32x32x16_bf16(a0T, w00, n0, 0, 0, 0);
        n0 = __builtin_amdgcn_mfma_f32_32x32x16_bf16(a1T, w01, n0, 0, 0, 0);
        n1 = __builtin_amdgcn_mfma_f32_32x32x16_bf16(a0T, w10, n1, 0, 0, 0);
        n1 = __builtin_amdgcn_mfma_f32_32x32x16_bf16(a1T, w11, n1, 0, 0, 0);
        bf16x8 z00 = *(const bf16x8*)&smZ[zb + n0off];
        bf16x8 z01 = *(const bf16x8*)&smZ[zb + n0off + 16];
        bf16x8 z10 = *(const bf16x8*)&smZ[zb + n1off];
        bf16x8 z11 = *(const bf16x8*)&smZ[zb + n1off + 16];
        n0 = __builtin_amdgcn_mfma_f32_32x32x16_bf16(z00, ilow,  n0, 0, 0, 0);
        n0 = __builtin_amdgcn_mfma_f32_32x32x16_bf16(z01, ihigh, n0, 0, 0, 0);
        n1 = __builtin_amdgcn_mfma_f32_32x32x16_bf16(z10, ilow,  n1, 0, 0, 0);
        n1 = __builtin_amdgcn_mfma_f32_32x32x16_bf16(z11, ihigh, n1, 0, 0, 0);
    }
    __syncthreads();                     // smZ node frag reads done before in-place silu

    // silu -> smH (aliases smZ)
    #pragma unroll
    for (int r = 0; r < 16; ++r) {
        int er = (r & 3) + 8 * (r >> 2) + rowbase;
        smH[er * SZ2 + wv * 32 + lo]       = f2bf_hu(silu_f(n0[r]));
        smH[er * SZ2 + (wv + 4) * 32 + lo] = f2bf_hu(silu_f(n1[r]));
    }
    __syncthreads();                     // smH complete

    // ---- GEMM2: [32 x 256] @ [256 x 128]; wave = 1 d-tile; depth-2 prefetch ----
    {
        const int d = wv * 32 + lo;
        f32x16 acc;
        float bb = bn2[d];
        #pragma unroll
        for (int r = 0; r < 16; ++r) acc[r] = bb;
        const int hoff = lo * SZ2 + hi * 8;
        const int wb = wv * (16 * 64 * 8) + lane * 8;
        bf16x8 bs2[2];
        bs2[0] = *(const bf16x8*)&W2s[wb];
        #pragma unroll
        for (int step = 0; step < 16; ++step) {
            const int cur = step & 1, nxt = cur ^ 1;
            if (step + 1 < 16)
                bs2[nxt] = *(const bf16x8*)&W2s[wb + (step + 1) * 512];
            bf16x8 af = *(const bf16x8*)&smH[hoff + step * 16];
            acc = __builtin_amdgcn_mfma_f32_32x32x16_bf16(af, bs2[cur], acc, 0, 0, 0);
        }
        __syncthreads();                 // smH reads done before smM overwrite
        #pragma unroll
        for (int r = 0; r < 16; ++r) {
            int er = (r & 3) + 8 * (r >> 2) + rowbase;
            smM[er * MSTR + d] = acc[r];
        }
    }
    __syncthreads();

    // ---- run-reduction over sorted dst; interior RMW / boundary atomics ----
    {
        const int g = t >> 5;            // 8 edge-strided groups
        const int d4 = (t & 31) * 4;
        for (int e0 = g; e0 < TE; e0 += 8) {
            if (e0 > 0 && didx[e0] == didx[e0 - 1]) continue;
            float4 s = *(const float4*)&smM[e0 * MSTR + d4];
            int er = e0 + 1;
            while (er < TE && didx[er] == didx[e0]) {
                float4 v = *(const float4*)&smM[er * MSTR + d4];
                s.x += v.x; s.y += v.y; s.z += v.z; s.w += v.w;
                ++er;
            }
            float* dp = &out[didx[e0] * NODE_DIM + d4];
            if (e0 > 0 && er < TE) {
                float4 cur = *(const float4*)dp;
                cur.x += s.x; cur.y += s.y; cur.z += s.z; cur.w += s.w;
                *(float4*)dp = cur;
            } else {
                atomicAdd(dp + 0, s.x); atomicAdd(dp + 1, s.y);
                atomicAdd(dp + 2, s.z); atomicAdd(dp + 3, s.w);
            }
        }
    }
    if (t < TE) {
        int e0 = t;
        if (e0 == 0 || didx[e0] != didx[e0 - 1]) {
            float sx = cxyz[e0], sy = cxyz[TE + e0], sz = cxyz[2 * TE + e0];
            int er = e0 + 1;
            while (er < TE && didx[er] == didx[e0]) {
                sx += cxyz[er]; sy += cxyz[TE + er]; sz += cxyz[2 * TE + er];
                ++er;
            }
            float* xo = out + N_NODES * NODE_DIM + didx[e0] * 3;
            if (e0 > 0 && er < TE) {
                xo[0] += sx; xo[1] += sy; xo[2] += sz;
            } else {
                atomicAdd(xo + 0, sx); atomicAdd(xo + 1, sy); atomicAdd(xo + 2, sz);
            }
        }
    }
}

// fallback: R6 kernel (TE=32, split accumulator), used when ws can't host tables.
__global__ __launch_bounds__(256, 6)
void egnn_mfma_kernel(const float* __restrict__ h, const float* __restrict__ x,
                      const void* __restrict__ ei, const float* __restrict__ dist,
                      const float* __restrict__ We1, const float* __restrict__ be1,
                      const float* __restrict__ bn2, const float* __restrict__ Wc2,
                      const float* __restrict__ biasC,
                      const unsigned short* __restrict__ W1s,
                      const unsigned short* __restrict__ W2s,
                      const int* __restrict__ perm,
                      const unsigned short* __restrict__ hbf,
                      float* __restrict__ out)
{
    __shared__ unsigned short smA[TE * ASTR];
    __shared__ int sidx[TE], didx[TE], eidx[TE];
    __shared__ float cw_s[TE];
    __shared__ float cxyz[3 * TE];

    unsigned short* smH2 = smA;
    float* smM = (float*)smA;

    const int t = threadIdx.x;
    const int lane = t & 63;
    const int wv = t >> 6;
    const int lo = lane & 31;
    const int hi = lane >> 5;
    const int swz = ((blockIdx.x & 7) * (NBLK / 8)) + (blockIdx.x >> 3);
    const int ebase = swz * TE;
    const int is64 = detect_is64(ei, t);

    if (t < 2 * TE) {
        int e = t & (TE - 1);
        int eid = perm[ebase + e];
        int which = t >> 5;
        long long pos = (long long)which * N_EDGES + eid;
        int idx = is64 ? (int)((const long long*)ei)[pos] : ((const int*)ei)[pos];
        if (which == 0) { sidx[e] = idx; eidx[e] = eid; }
        else didx[e] = idx;
        if (t < TE) cw_s[t] = 0.0f;
    }
    __syncthreads();

    if (hbf != nullptr) {
        #pragma unroll
        for (int it = 0; it < 4; ++it) {
            int id = it * 256 + t;
            int g = id & 15;
            int half = (id >> 4) & 1;
            int e = id >> 5;
            int node = half ? didx[e] : sidx[e];
            uint4 v = *(const uint4*)&hbf[node * NODE_DIM + 8 * g];
            *(uint4*)&smA[e * ASTR + half * NODE_DIM + 8 * g] = v;
        }
    } else {
        #pragma unroll
        for (int it = 0; it < 4; ++it) {
            int id = it * 256 + t;
            int g8 = id & 15;
            int half = (id >> 4) & 1;
            int e = id >> 5;
            int node = half ? didx[e] : sidx[e];
            const float4* p = (const float4*)&h[node * NODE_DIM + 8 * g8];
            float4 v0 = p[0], v1 = p[1];
            unsigned int a0 = pkbf(v0.x, v0.y), a1 = pkbf(v0.z, v0.w);
            unsigned int a2 = pkbf(v1.x, v1.y), a3 = pkbf(v1.z, v1.w);
            *(uint4*)&smA[e * ASTR + half * NODE_DIM + 8 * g8] = make_uint4(a0, a1, a2, a3);
        }
    }
    {
        int e = t >> 3;
        int j4 = (t & 7) * 4;
        float d = dist[eidx[e]];
        float s0 = silu_f(d * We1[j4 + 0] + be1[j4 + 0]);
        float s1 = silu_f(d * We1[j4 + 1] + be1[j4 + 1]);
        float s2 = silu_f(d * We1[j4 + 2] + be1[j4 + 2]);
        float s3 = silu_f(d * We1[j4 + 3] + be1[j4 + 3]);
        *(uint2*)&smA[e * ASTR + 2 * NODE_DIM + j4] = make_uint2(pkbf(s0, s1), pkbf(s2, s3));
    }
    if (t < TE) {
        int s = sidx[t], dn = didx[t];
        float dx = x[s * 3 + 0] - x[dn * 3 + 0];
        float dy = x[s * 3 + 1] - x[dn * 3 + 1];
        float dz = x[s * 3 + 2] - x[dn * 3 + 2];
        float len = fmaxf(sqrtf(dx * dx + dy * dy + dz * dz), 1e-8f);
        float inv = 1.0f / len;
        cxyz[t] = dx * inv; cxyz[TE + t] = dy * inv; cxyz[2 * TE + t] = dz * inv;
    }
    __syncthreads();

    const int rowbase = 4 * hi;

    {
        f32x16 c0, c1;
        {
            float b0 = biasC[256 + wv * 32 + lo];
            float b1 = biasC[256 + (wv + 4) * 32 + lo];
            #pragma unroll
            for (int r = 0; r < 16; ++r) { c0[r] = b0; c1[r] = b1; }
        }
        {
            const int ao = lo * ASTR + hi * 8;
            const int TS = 18 * 64 * 8;
            const int q0 = (8 + wv) * TS + lane * 8;
            const int q1 = (12 + wv) * TS + lane * 8;
            bf16x8 p0[2], p1[2];
            p0[0] = *(const bf16x8*)&W1s[q0];
            p1[0] = *(const bf16x8*)&W1s[q1];
            #pragma unroll
            for (int step = 0; step < 18; ++step) {
                const int cur = step & 1, nxt = cur ^ 1;
                if (step + 1 < 18) {
                    p0[nxt] = *(const bf16x8*)&W1s[q0 + (step + 1) * 512];
                    p1[nxt] = *(const bf16x8*)&W1s[q1 + (step + 1) * 512];
                }
                bf16x8 f = *(const bf16x8*)&smA[ao + step * 16];
                c0 = __builtin_amdgcn_mfma_f32_32x32x16_bf16(f, p0[cur], c0, 0, 0, 0);
                c1 = __builtin_amdgcn_mfma_f32_32x32x16_bf16(f, p1[cur], c1, 0, 0, 0);
            }
        }
        float w0 = Wc2[wv * 32 + lo];
        float w1 = Wc2[(wv + 4) * 32 + lo];
        float p[16];
        #pragma unroll
        for (int r = 0; r < 16; ++r)
            p[r] = silu_f(c0[r]) * w0 + silu_f(c1[r]) * w1;
        #pragma unroll
        for (int off = 1; off < 32; off <<= 1) {
            #pragma unroll
            for (int r = 0; r < 16; ++r) p[r] += __shfl_xor(p[r], off);
        }
        if (lo == 0) {
            #pragma unroll
            for (int r = 0; r < 16; ++r)
                atomicAdd(&cw_s[(r & 3) + 8 * (r >> 2) + rowbase], p[r]);
        }
    }

    f32x16 a0, a1;
    {
        float b0 = biasC[wv * 32 + lo];
        float b1 = biasC[(wv + 4) * 32 + lo];
        #pragma unroll
        for (int r = 0; r < 16; ++r) { a0[r] = b0; a1[r] = b1; }
        const int ao = lo * ASTR + hi * 8;
        const int TS = 18 * 64 * 8;
        const int q0 = (wv) * TS + lane * 8;
        const int q1 = (wv + 4) * TS + lane * 8;
        bf16x8 p0[2], p1[2];
        p0[0] = *(const bf16x8*)&W1s[q0];
        p1[0] = *(const bf16x8*)&W1s[q1];
        #pragma unroll
        for (int step = 0; step < 18; ++step) {
            const int cur = step & 1, nxt = cur ^ 1;
            if (step + 1 < 18) {
                p0[nxt] = *(const bf16x8*)&W1s[q0 + (step + 1) * 512];
                p1[nxt] = *(const bf16x8*)&W1s[q1 + (step + 1) * 512];
            }
            bf16x8 f = *(const bf16x8*)&smA[ao + step * 16];
            a0 = __builtin_amdgcn_mfma_f32_32x32x16_bf16(f, p0[cur], a0, 0, 0, 0);
            a1 = __builtin_amdgcn_mfma_f32_32x32x16_bf16(f, p1[cur], a1, 0, 0, 0);
        }
    }
    __syncthreads();

    {
        const int jb0 = (wv    ) * 32 + lo;
        const int jb1 = (wv + 4) * 32 + lo;
        #pragma unroll
        for (int r = 0; r < 16; ++r) {
            int er = (r & 3) + 8 * (r >> 2) + rowbase;
            smH2[er * HSTR + jb0] = f2bf_hu(silu_f(a0[r]));
            smH2[er * HSTR + jb1] = f2bf_hu(silu_f(a1[r]));
        }
    }
    if (t < TE) {
        float w = cw_s[t];
        cxyz[t] *= w; cxyz[TE + t] *= w; cxyz[2 * TE + t] *= w;
    }
    __syncthreads();

    {
        const int d = wv * 32 + lo;
        f32x16 acc;
        float bb = bn2[d];
        #pragma unroll
        for (int r = 0; r < 16; ++r) acc[r] = bb;
        const int hoff = lo * HSTR + hi * 8;
        const int wb = wv * (16 * 64 * 8) + lane * 8;
        bf16x8 bs2[2];
        bs2[0] = *(const bf16x8*)&W2s[wb];
        #pragma unroll
        for (int step = 0; step < 16; ++step) {
            const int cur = step & 1, nxt = cur ^ 1;
            if (step + 1 < 16)
                bs2[nxt] = *(const bf16x8*)&W2s[wb + (step + 1) * 512];
            bf16x8 af = *(const bf16x8*)&smH2[hoff + step * 16];
            acc = __builtin_amdgcn_mfma_f32_32x32x16_bf16(af, bs2[cur], acc, 0, 0, 0);
        }
        __syncthreads();
        #pragma unroll
        for (int r = 0; r < 16; ++r) {
            int er = (r & 3) + 8 * (r >> 2) + rowbase;
            smM[er * MSTR + d] = acc[r];
        }
    }
    __syncthreads();

    {
        const int g = t >> 5;
        const int d4 = (t & 31) * 4;
        for (int e0 = g; e0 < TE; e0 += 8) {
            if (e0 > 0 && didx[e0] == didx[e0 - 1]) continue;
            float4 s = *(const float4*)&smM[e0 * MSTR + d4];
            int er = e0 + 1;
            while (er < TE && didx[er] == didx[e0]) {
                float4 v = *(const float4*)&smM[er * MSTR + d4];
                s.x += v.x; s.y += v.y; s.z += v.z; s.w += v.w;
                ++er;
            }
            float* dp = &out[didx[e0] * NODE_DIM + d4];
            if (e0 > 0 && er < TE) {
                float4 cur = *(const float4*)dp;
                cur.x += s.x; cur.y += s.y; cur.z += s.z; cur.w += s.w;
                *(float4*)dp = cur;
            } else {
                atomicAdd(dp + 0, s.x); atomicAdd(dp + 1, s.y);
                atomicAdd(dp + 2, s.z); atomicAdd(dp + 3, s.w);
            }
        }
    }
    if (t < TE) {
        int e0 = t;
        if (e0 == 0 || didx[e0] != didx[e0 - 1]) {
            float sx = cxyz[e0], sy = cxyz[TE + e0], sz = cxyz[2 * TE + e0];
            int er = e0 + 1;
            while (er < TE && didx[er] == didx[e0]) {
                sx += cxyz[er]; sy += cxyz[TE + er]; sz += cxyz[2 * TE + er];
                ++er;
            }
            float* xo = out + N_NODES * NODE_DIM + didx[e0] * 3;
            if (e0 > 0 && er < TE) {
                xo[0] += sx; xo[1] += sy; xo[2] += sz;
            } else {
                atomicAdd(xo + 0, sx); atomicAdd(xo + 1, sy); atomicAdd(xo + 2, sz);
            }
        }
    }
}

extern "C" void kernel_launch(void* const* d_in, const int* in_sizes, int n_in,
                              void* d_out, int out_size, void* d_ws, size_t ws_size,
                              hipStream_t stream) {
    const float* h    = (const float*)d_in[0];
    const float* x    = (const float*)d_in[1];
    const void*  ei   = d_in[2];
    const float* dist = (const float*)d_in[3];
    const float* We1  = (const float*)d_in[4];
    const float* be1  = (const float*)d_in[5];
    const float* We2  = (const float*)d_in[6];
    const float* be2  = (const float*)d_in[7];
    const float* Wn1  = (const float*)d_in[8];
    const float* bn1  = (const float*)d_in[9];
    const float* Wn2  = (const float*)d_in[10];
    const float* bn2  = (const float*)d_in[11];
    const float* Wc1  = (const float*)d_in[12];
    const float* bc1  = (const float*)d_in[13];
    const float* Wc2  = (const float*)d_in[14];
    float* out = (float*)d_out;

    float* biasC = (float*)((char*)d_ws + WS_BIAS_OFF);
    unsigned short* W1s = (unsigned short*)((char*)d_ws + WS_W1S_OFF);
    unsigned short* W2s = (unsigned short*)((char*)d_ws + WS_W2S_OFF);
    int* counts   = (int*)((char*)d_ws + WS_CNT_OFF);
    int* cursor   = (int*)((char*)d_ws + WS_CUR_OFF);
    int* perm     = (int*)((char*)d_ws + WS_PERM_OFF);
    unsigned short* hbf = (ws_size >= (size_t)WS_HBF_END)
                        ? (unsigned short*)((char*)d_ws + WS_HBF_OFF) : nullptr;
    int use_pp = (ws_size >= (size_t)WS_PD_END && hbf != nullptr) ? 1 : 0;
    unsigned short* psrc = use_pp ? (unsigned short*)((char*)d_ws + WS_PS_OFF) : nullptr;
    unsigned short* pdst = use_pp ? (unsigned short*)((char*)d_ws + WS_PD_OFF) : nullptr;

    hipMemsetAsync(counts, 0, N_NODES * sizeof(int), stream);

    prep_hist_kernel<<<PREP_TOT / 256, 256, 0, stream>>>(
        h, x, ei, We2, be2, Wn1, bn1, Wn2, Wc1, bc1,
        out, biasC, W1s, W2s, counts, hbf, use_pp);

    scan_fused_kernel<<<128, 256, 0, stream>>>(counts, cursor);

    if (use_pp) {
        place_nterm_kernel<<<PLACE_BLKS + NT_BLKS, 256, 0, stream>>>(
            ei, cursor, perm, hbf, W1s, psrc, pdst);
        egnn_pp_kernel<<<NBLK, 256, 0, stream>>>(
            x, ei, dist, We1, be1, bn2, Wc2, biasC, W1s, W2s, perm, psrc, pdst, out);
    } else {
        place_kernel<<<PLACE_BLKS, 256, 0, stream>>>(ei, cursor, perm);
        egnn_mfma_kernel<<<NBLK, 256, 0, stream>>>(
            h, x, ei, dist, We1, be1, bn2, Wc2, biasC, W1s, W2s, perm, hbf, out);
    }
}

// Round 14
// 400.167 us; speedup vs baseline: 1.1152x; 1.0885x over previous
//
#include <hip/hip_runtime.h>
#include <math.h>

#define N_NODES 32768
#define N_EDGES 524288
#define NODE_DIM 128
#define HIDDEN 256
#define EDGE_DIM 32
#define TE 32              // edges per block
#define NBLK (N_EDGES / TE)
#define ASTR 296           // fallback smA row stride (bf16)
#define HSTR 264           // fallback smH row stride (bf16)
#define SZ2  264           // pp smZ/smH row stride (bf16): 528 B, 16B-aligned
#define MSTR 132           // smM row stride (f32): 528 B, 16B-aligned

typedef __attribute__((ext_vector_type(8))) short bf16x8;
typedef __attribute__((ext_vector_type(16))) float f32x16;

__device__ __forceinline__ float silu_f(float v) {
    float e = __expf(-v);
    return v * __builtin_amdgcn_rcpf(1.0f + e);
}

__device__ __forceinline__ unsigned short f2bf_rne(float f) {
    union { float f; unsigned int u; } v; v.f = f;
    return (unsigned short)((v.u + 0x7fffu + ((v.u >> 16) & 1u)) >> 16);
}
__device__ __forceinline__ unsigned int pk_rne(float a, float b) {
    return (unsigned int)f2bf_rne(a) | ((unsigned int)f2bf_rne(b) << 16);
}
// half-up pack of two floats -> (bf16(a) | bf16(b)<<16)
__device__ __forceinline__ unsigned int pkbf(float a, float b) {
    union { float f; unsigned int u; } ua, ub; ua.f = a; ub.f = b;
    return __builtin_amdgcn_perm(ub.u + 0x8000u, ua.u + 0x8000u, 0x07060302u);
}
__device__ __forceinline__ unsigned short f2bf_hu(float f) {
    union { float f; unsigned int u; } v; v.f = f;
    return (unsigned short)((v.u + 0x8000u) >> 16);
}
__device__ __forceinline__ float bfu(unsigned short u) {
    union { unsigned int u; float f; } v; v.u = ((unsigned int)u) << 16;
    return v.f;
}
// packed bf16x2 + bf16x2 -> bf16x2 (f32 math, half-up repack)
__device__ __forceinline__ unsigned int addbf2(unsigned int a, unsigned int b) {
    float l = __uint_as_float(a << 16) + __uint_as_float(b << 16);
    float h = __uint_as_float(a & 0xffff0000u) + __uint_as_float(b & 0xffff0000u);
    return pkbf(l, h);
}

// uniform idx-width check: lanes sample the first 64 high words of ei.
__device__ __forceinline__ int detect_is64(const void* ei, int t) {
    const unsigned int* ew = (const unsigned int*)ei;
    unsigned int hiw = ew[2 * (t & 63) + 1];
    return (__ballot(hiw != 0u) == 0ULL) ? 1 : 0;
}

// ws layout (bytes)
#define WS_BIAS_OFF 1024
#define WS_W1S_OFF  69632
#define WS_W2S_OFF  364544
#define WS_CNT_OFF  430080
#define WS_CUR_OFF  561152
#define WS_PERM_OFF 692224
#define WS_HBF_OFF  2790400
#define WS_HBF_END  (WS_HBF_OFF + N_NODES * NODE_DIM * 2)          // 11179008
#define WS_PS_OFF   WS_HBF_END
#define WS_PD_OFF   (WS_PS_OFF + N_NODES * 512 * 2)                // 44733440
#define WS_PD_END   (WS_PD_OFF + N_NODES * 512 * 2)                // 78287872

#define SEG_HIST 524288
#define SEG_W1S  147456
#define SEG_W2S  32768
#define SEG_BIAS 512
#define SEG_OUT  1073152
#define SEG_HBF  524288
#define PREP_TOT (SEG_HIST + SEG_W1S + SEG_W2S + SEG_BIAS + SEG_OUT + SEG_HBF)

// pp-mode W1s sublayout (shorts): [0,16384) part A = K=32 folded-t1 frags;
// [16384,81920) part B = rows 0..127 (psrc); [81920,147456) part C = rows 128..255 (pdst)
#define W1_PA 0
#define W1_PB 16384
#define W1_PC 81920

// merged place+nterm grid split
#define PLACE_BLKS (N_EDGES / 256)     // 2048
#define NT_BLKS    (N_NODES / 32)      // 1024

__device__ __forceinline__ float w1row(const float* Wn1, const float* Wc1, int k, int n) {
    return (n < 256) ? Wn1[k * 256 + n] : Wc1[k * 256 + (n - 256)];
}

// merged prep + hist: counts must be zeroed (hipMemsetAsync) before this kernel.
__global__ void prep_hist_kernel(const float* __restrict__ h, const float* __restrict__ x,
                                 const void* __restrict__ ei,
                                 const float* __restrict__ We2, const float* __restrict__ be2,
                                 const float* __restrict__ Wn1, const float* __restrict__ bn1,
                                 const float* __restrict__ Wn2,
                                 const float* __restrict__ Wc1, const float* __restrict__ bc1,
                                 float* __restrict__ out, float* __restrict__ biasC,
                                 unsigned short* __restrict__ W1s, unsigned short* __restrict__ W2s,
                                 int* __restrict__ counts, unsigned short* __restrict__ hbf,
                                 int use_pp) {
    int i = blockIdx.x * 256 + threadIdx.x;
    if (i < SEG_HIST) {
        int is64 = detect_is64(ei, threadIdx.x);
        int dst = is64 ? (int)((const long long*)ei)[N_EDGES + i]
                       : ((const int*)ei)[N_EDGES + i];
        atomicAdd(&counts[dst], 1);
        return;
    }
    i -= SEG_HIST;
    if (i < SEG_W1S) {
        if (use_pp) {
            if (i < W1_PB) {
                // part A: K=32, rows = folded edge-MLP layer 2 (orig rows 256..287)
                int jj = i & 7, ln = (i >> 3) & 63, rest = i >> 9;   // rest 0..31
                int step = rest & 1, tile = rest >> 1;
                int n = tile * 32 + (ln & 31);
                int j = step * 16 + ((ln >> 5) * 8) + jj;            // 0..31
                float s = 0.0f;
                #pragma unroll 8
                for (int q = 0; q < 32; ++q)
                    s += We2[j * 32 + q] * w1row(Wn1, Wc1, 256 + q, n);
                W1s[i] = f2bf_rne(s);
            } else if (i < W1_PC) {
                // part B: K=128, rows 0..127 (src half) for psrc node-GEMM
                int i2 = i - W1_PB;
                int jj = i2 & 7, ln = (i2 >> 3) & 63, rest = i2 >> 9; // 0..127
                int step = rest & 7, tile = rest >> 3;
                int n = tile * 32 + (ln & 31);
                int k = step * 16 + ((ln >> 5) * 8) + jj;
                W1s[i] = f2bf_rne(w1row(Wn1, Wc1, k, n));
            } else {
                // part C: K=128, rows 128..255 (dst half) for pdst node-GEMM
                int i2 = i - W1_PC;
                int jj = i2 & 7, ln = (i2 >> 3) & 63, rest = i2 >> 9;
                int step = rest & 7, tile = rest >> 3;
                int n = tile * 32 + (ln & 31);
                int k = 128 + step * 16 + ((ln >> 5) * 8) + jj;
                W1s[i] = f2bf_rne(w1row(Wn1, Wc1, k, n));
            }
        } else {
            // fallback layout: K=288, 18 steps; layer 2 folded for k >= 256
            int jj = i & 7, ln = (i >> 3) & 63, rest = i >> 9;
            int step = rest % 18, tile = rest / 18;
            int n = tile * 32 + (ln & 31);
            int k = step * 16 + ((ln >> 5) * 8) + jj;
            float v;
            if (k < 256) {
                v = w1row(Wn1, Wc1, k, n);
            } else {
                int j = k - 256;
                float s = 0.0f;
                #pragma unroll 8
                for (int q = 0; q < 32; ++q)
                    s += We2[j * 32 + q] * w1row(Wn1, Wc1, 256 + q, n);
                v = s;
            }
            W1s[i] = f2bf_rne(v);
        }
        return;
    }
    i -= SEG_W1S;
    if (i < SEG_W2S) {
        int jj = i & 7, ln = (i >> 3) & 63, rest = i >> 9;
        int step = rest & 15, tile = rest >> 4;
        int d = tile * 32 + (ln & 31);
        int k = step * 16 + ((ln >> 5) * 8) + jj;
        W2s[i] = f2bf_rne(Wn2[k * 128 + d]);
        return;
    }
    i -= SEG_W2S;
    if (i < SEG_BIAS) {
        int n = i;
        float s = (n < 256) ? bn1[n] : bc1[n - 256];
        #pragma unroll 8
        for (int q = 0; q < 32; ++q)
            s += be2[q] * w1row(Wn1, Wc1, 256 + q, n);
        biasC[n] = s;
        return;
    }
    i -= SEG_BIAS;
    if (i < SEG_OUT) {
        const int NH4 = N_NODES * NODE_DIM / 4;
        const float4* h4 = (const float4*)h;
        const float4* x4 = (const float4*)x;
        ((float4*)out)[i] = (i < NH4) ? h4[i] : x4[i - NH4];
        return;
    }
    i -= SEG_OUT;
    if (hbf != nullptr && i < SEG_HBF) {
        const float4* p = (const float4*)&h[i * 8];
        float4 v0 = p[0], v1 = p[1];
        uint4 o = make_uint4(pk_rne(v0.x, v0.y), pk_rne(v0.z, v0.w),
                             pk_rne(v1.x, v1.y), pk_rne(v1.z, v1.w));
        *(uint4*)&hbf[i * 8] = o;
    }
}

// fused scan: 128 blocks; each block redundantly computes all 128 chunk partials
__global__ __launch_bounds__(256)
void scan_fused_kernel(const int* __restrict__ counts, int* __restrict__ cursor) {
    __shared__ int pb[128];
    __shared__ int loc[256];
    const int t = threadIdx.x;
    const int b = blockIdx.x;
    if (t < 128) {
        const int4* c4 = (const int4*)(counts + t * 256);
        int s = 0;
        #pragma unroll 8
        for (int i = 0; i < 64; ++i) { int4 v = c4[i]; s += v.x + v.y + v.z + v.w; }
        pb[t] = s;
    }
    int c = counts[b * 256 + t];
    loc[t] = c;
    __syncthreads();
    if (t == 0) {
        int s = 0;
        for (int j = 0; j < 128; ++j) { int v = pb[j]; pb[j] = s; s += v; }
    }
    #pragma unroll
    for (int d = 1; d < 256; d <<= 1) {
        int v = (t >= d) ? loc[t - d] : 0;
        __syncthreads();
        loc[t] += v;
        __syncthreads();
    }
    cursor[b * 256 + t] = pb[b] + loc[t] - c;   // exclusive
}

// merged place + nterm: blocks [0,PLACE_BLKS) scatter edge ids into perm;
// blocks [PLACE_BLKS, PLACE_BLKS+NT_BLKS) compute psrc/pdst node-GEMMs.
__global__ __launch_bounds__(256, 4)
void place_nterm_kernel(const void* __restrict__ ei,
                        int* __restrict__ cursor, int* __restrict__ perm,
                        const unsigned short* __restrict__ hbf,
                        const unsigned short* __restrict__ W1s,
                        unsigned short* __restrict__ psrc,
                        unsigned short* __restrict__ pdst) {
    if (blockIdx.x < PLACE_BLKS) {
        int is64 = detect_is64(ei, threadIdx.x);
        int e = blockIdx.x * 256 + threadIdx.x;
        int dst = is64 ? (int)((const long long*)ei)[N_EDGES + e]
                       : ((const int*)ei)[N_EDGES + e];
        int pos = atomicAdd(&cursor[dst], 1);
        perm[pos] = e;
        return;
    }
    // nterm role
    const int t = threadIdx.x;
    const int lane = t & 63;
    const int wv = t >> 6;
    const int lo = lane & 31;
    const int hi = lane >> 5;
    const int nb = (blockIdx.x - PLACE_BLKS) * 32;
    const int aoff = (nb + lo) * NODE_DIM + hi * 8;
    const int TSB = 8 * 64 * 8;          // 4096 shorts per n-tile

    for (int pass = 0; pass < 2; ++pass) {
        const unsigned short* WB = W1s + (pass ? W1_PC : W1_PB);
        unsigned short* outp = pass ? pdst : psrc;
        f32x16 a0, a1, a2, a3;
        #pragma unroll
        for (int r = 0; r < 16; ++r) { a0[r] = 0.f; a1[r] = 0.f; a2[r] = 0.f; a3[r] = 0.f; }
        const int b0 = (wv     ) * TSB + lane * 8;
        const int b1 = (wv +  4) * TSB + lane * 8;
        const int b2 = (wv +  8) * TSB + lane * 8;
        const int b3 = (wv + 12) * TSB + lane * 8;
        bf16x8 p0[2], p1[2], p2[2], p3[2];
        p0[0] = *(const bf16x8*)&WB[b0];
        p1[0] = *(const bf16x8*)&WB[b1];
        p2[0] = *(const bf16x8*)&WB[b2];
        p3[0] = *(const bf16x8*)&WB[b3];
        #pragma unroll
        for (int step = 0; step < 8; ++step) {
            const int cur = step & 1, nxt = cur ^ 1;
            if (step + 1 < 8) {
                p0[nxt] = *(const bf16x8*)&WB[b0 + (step + 1) * 512];
                p1[nxt] = *(const bf16x8*)&WB[b1 + (step + 1) * 512];
                p2[nxt] = *(const bf16x8*)&WB[b2 + (step + 1) * 512];
                p3[nxt] = *(const bf16x8*)&WB[b3 + (step + 1) * 512];
            }
            bf16x8 f = *(const bf16x8*)&hbf[aoff + step * 16];
            a0 = __builtin_amdgcn_mfma_f32_32x32x16_bf16(f, p0[cur], a0, 0, 0, 0);
            a1 = __builtin_amdgcn_mfma_f32_32x32x16_bf16(f, p1[cur], a1, 0, 0, 0);
            a2 = __builtin_amdgcn_mfma_f32_32x32x16_bf16(f, p2[cur], a2, 0, 0, 0);
            a3 = __builtin_amdgcn_mfma_f32_32x32x16_bf16(f, p3[cur], a3, 0, 0, 0);
        }
        #pragma unroll
        for (int r = 0; r < 16; ++r) {
            int er = (r & 3) + 8 * (r >> 2) + 4 * hi;
            unsigned short* row = &outp[(unsigned)(nb + er) * 512 + lo];
            row[(wv     ) * 32] = f2bf_rne(a0[r]);
            row[(wv +  4) * 32] = f2bf_rne(a1[r]);
            row[(wv +  8) * 32] = f2bf_rne(a2[r]);
            row[(wv + 12) * 32] = f2bf_rne(a3[r]);
        }
    }
}

// standalone place (non-pp fallback path)
__global__ void place_kernel(const void* __restrict__ ei,
                             int* __restrict__ cursor, int* __restrict__ perm) {
    int is64 = detect_is64(ei, threadIdx.x);
    int e = blockIdx.x * 256 + threadIdx.x;
    int dst = is64 ? (int)((const long long*)ei)[N_EDGES + e]
                   : ((const int*)ei)[N_EDGES + e];
    int pos = atomicAdd(&cursor[dst], 1);
    perm[pos] = e;
}

// pp edge kernel (R11 measured-best config, launch_bounds(256,6)): fused addbf2
// staging + identity-B MFMA adds reading smZ vector fragments.
// NOTE: bound 7 (R13) raised occupancy 57->70 but thrashed L3 (FETCH +120 MB,
// WRITE +213 MB, dur +29 us). ~57% occupancy is this kernel's cache-residency knee.
__global__ __launch_bounds__(256, 6)
void egnn_pp_kernel(const float* __restrict__ x,
                    const void* __restrict__ ei, const float* __restrict__ dist,
                    const float* __restrict__ We1, const float* __restrict__ be1,
                    const float* __restrict__ bn2, const float* __restrict__ Wc2,
                    const float* __restrict__ biasC,
                    const unsigned short* __restrict__ W1s,
                    const unsigned short* __restrict__ W2s,
                    const int* __restrict__ perm,
                    const unsigned short* __restrict__ psrc,
                    const unsigned short* __restrict__ pdst,
                    float* __restrict__ out)
{
    __shared__ unsigned short smZ[TE * SZ2];     // 16896 B; staging / smH / smM alias
    __shared__ unsigned short smT[TE * 40];      // 2560 B: t1 tile [32][32+pad]
    __shared__ int sidx[TE], didx[TE], eidx[TE];
    __shared__ float cw_s[TE];
    __shared__ float cxyz[3 * TE];

    unsigned short* smH = smZ;
    float* smM = (float*)smZ;

    const int t = threadIdx.x;           // 0..255
    const int lane = t & 63;
    const int wv = t >> 6;               // 0..3
    const int lo = lane & 31;
    const int hi = lane >> 5;
    const int swz = ((blockIdx.x & 7) * (NBLK / 8)) + (blockIdx.x >> 3);
    const int ebase = swz * TE;
    const int is64 = detect_is64(ei, t);

    // ---- 1. permuted edge indices + zero cw ----
    if (t < 2 * TE) {
        int e = t & (TE - 1);
        int eid = perm[ebase + e];
        int which = t >> 5;              // 0 = src, 1 = dst
        long long pos = (long long)which * N_EDGES + eid;
        int idx = is64 ? (int)((const long long*)ei)[pos] : ((const int*)ei)[pos];
        if (which == 0) { sidx[e] = idx; eidx[e] = eid; }
        else didx[e] = idx;
        if (t < TE) cw_s[t] = 0.0f;
    }
    __syncthreads();

    // ---- 2. t1 -> smT, unit dirs, stage summed coord cols (256..511) ----
    {
        int e = t >> 3;                  // 0..31
        int j4 = (t & 7) * 4;
        float d = dist[eidx[e]];
        float s0 = silu_f(d * We1[j4 + 0] + be1[j4 + 0]);
        float s1 = silu_f(d * We1[j4 + 1] + be1[j4 + 1]);
        float s2 = silu_f(d * We1[j4 + 2] + be1[j4 + 2]);
        float s3 = silu_f(d * We1[j4 + 3] + be1[j4 + 3]);
        *(uint2*)&smT[e * 40 + j4] = make_uint2(pkbf(s0, s1), pkbf(s2, s3));
    }
    if (t < TE) {
        int s = sidx[t], dn = didx[t];
        float dx = x[s * 3 + 0] - x[dn * 3 + 0];
        float dy = x[s * 3 + 1] - x[dn * 3 + 1];
        float dz = x[s * 3 + 2] - x[dn * 3 + 2];
        float len = fmaxf(sqrtf(dx * dx + dy * dy + dz * dz), 1e-8f);
        float inv = 1.0f / len;
        cxyz[t] = dx * inv; cxyz[TE + t] = dy * inv; cxyz[2 * TE + t] = dz * inv;
    }
    #pragma unroll
    for (int it = 0; it < 4; ++it) {
        int id = it * 256 + t;
        int g = id & 31;                 // 8-col unit within 256
        int e = id >> 5;                 // 0..31
        uint4 a = *(const uint4*)&psrc[(unsigned)sidx[e] * 512 + 256 + g * 8];
        uint4 b = *(const uint4*)&pdst[(unsigned)didx[e] * 512 + 256 + g * 8];
        uint4 o = make_uint4(addbf2(a.x, b.x), addbf2(a.y, b.y),
                             addbf2(a.z, b.z), addbf2(a.w, b.w));
        *(uint4*)&smZ[e * SZ2 + g * 8] = o;
    }
    __syncthreads();

    const int rowbase = 4 * hi;
    const int aT = lo * 40 + hi * 8;     // smT fragment base
    const int zb = lo * SZ2 + hi * 8;    // smZ fragment base (lane lo = edge row)

    // identity B-fragments: B_low[k][n]=d(k,n), B_high[k][n]=d(k,n-16)
    bf16x8 ilow, ihigh;
    #pragma unroll
    for (int ii = 0; ii < 8; ++ii) {
        int k = hi * 8 + ii;
        ilow[ii]  = (short)((k == lo)      ? 0x3F80 : 0);
        ihigh[ii] = (short)((k == lo - 16) ? 0x3F80 : 0);
    }

    bf16x8 a0T = *(const bf16x8*)&smT[aT];
    bf16x8 a1T = *(const bf16x8*)&smT[aT + 16];

    // ---- 3a. coord tiles (8+wv, 12+wv): mini-GEMM + identity Z-adds + c-reduce ----
    {
        const int c0off = wv * 32;
        const int c1off = (wv + 4) * 32;
        f32x16 c0, c1;
        {
            float b0 = biasC[256 + c0off + lo];
            float b1 = biasC[256 + c1off + lo];
            #pragma unroll
            for (int r = 0; r < 16; ++r) { c0[r] = b0; c1[r] = b1; }
        }
        const int tt0 = 8 + wv, tt1 = 12 + wv;
        bf16x8 w00 = *(const bf16x8*)&W1s[((tt0 * 2 + 0) * 64 + lane) * 8];
        bf16x8 w01 = *(const bf16x8*)&W1s[((tt0 * 2 + 1) * 64 + lane) * 8];
        bf16x8 w10 = *(const bf16x8*)&W1s[((tt1 * 2 + 0) * 64 + lane) * 8];
        bf16x8 w11 = *(const bf16x8*)&W1s[((tt1 * 2 + 1) * 64 + lane) * 8];
        c0 = __builtin_amdgcn_mfma_f32_32x32x16_bf16(a0T, w00, c0, 0, 0, 0);
        c0 = __builtin_amdgcn_mfma_f32_32x32x16_bf16(a1T, w01, c0, 0, 0, 0);
        c1 = __builtin_amdgcn_mfma_f32_32x32x16_bf16(a0T, w10, c1, 0, 0, 0);
        c1 = __builtin_amdgcn_mfma_f32_32x32x16_bf16(a1T, w11, c1, 0, 0, 0);
        bf16x8 z00 = *(const bf16x8*)&smZ[zb + c0off];
        bf16x8 z01 = *(const bf16x8*)&smZ[zb + c0off + 16];
        bf16x8 z10 = *(const bf16x8*)&smZ[zb + c1off];
        bf16x8 z11 = *(const bf16x8*)&smZ[zb + c1off + 16];
        c0 = __builtin_amdgcn_mfma_f32_32x32x16_bf16(z00, ilow,  c0, 0, 0, 0);
        c0 = __builtin_amdgcn_mfma_f32_32x32x16_bf16(z01, ihigh, c0, 0, 0, 0);
        c1 = __builtin_amdgcn_mfma_f32_32x32x16_bf16(z10, ilow,  c1, 0, 0, 0);
        c1 = __builtin_amdgcn_mfma_f32_32x32x16_bf16(z11, ihigh, c1, 0, 0, 0);
        float wc0 = Wc2[c0off + lo];
        float wc1 = Wc2[c1off + lo];
        float p[16];
        #pragma unroll
        for (int r = 0; r < 16; ++r)
            p[r] = silu_f(c0[r]) * wc0 + silu_f(c1[r]) * wc1;
        #pragma unroll
        for (int off = 1; off < 32; off <<= 1) {
            #pragma unroll
            for (int r = 0; r < 16; ++r) p[r] += __shfl_xor(p[r], off);
        }
        if (lo == 0) {
            #pragma unroll
            for (int r = 0; r < 16; ++r)
                atomicAdd(&cw_s[(r & 3) + 8 * (r >> 2) + rowbase], p[r]);
        }
    }
    __syncthreads();                     // smZ coord frag reads done; cw atomics visible

    // ---- 4. stage summed node cols (0..255); scale cxyz by final cw ----
    #pragma unroll
    for (int it = 0; it < 4; ++it) {
        int id = it * 256 + t;
        int g = id & 31;
        int e = id >> 5;
        uint4 a = *(const uint4*)&psrc[(unsigned)sidx[e] * 512 + g * 8];
        uint4 b = *(const uint4*)&pdst[(unsigned)didx[e] * 512 + g * 8];
        uint4 o = make_uint4(addbf2(a.x, b.x), addbf2(a.y, b.y),
                             addbf2(a.z, b.z), addbf2(a.w, b.w));
        *(uint4*)&smZ[e * SZ2 + g * 8] = o;
    }
    if (t < TE) {
        float w = cw_s[t];
        cxyz[t] *= w; cxyz[TE + t] *= w; cxyz[2 * TE + t] *= w;
    }
    __syncthreads();

    // ---- 5. node tiles (wv, wv+4): mini-GEMM + identity Z-adds ----
    f32x16 n0, n1;
    {
        const int n0off = wv * 32;
        const int n1off = (wv + 4) * 32;
        float b0 = biasC[n0off + lo];
        float b1 = biasC[n1off + lo];
        #pragma unroll
        for (int r = 0; r < 16; ++r) { n0[r] = b0; n1[r] = b1; }
        const int tt0 = wv, tt1 = wv + 4;
        bf16x8 w00 = *(const bf16x8*)&W1s[((tt0 * 2 + 0) * 64 + lane) * 8];
        bf16x8 w01 = *(const bf16x8*)&W1s[((tt0 * 2 + 1) * 64 + lane) * 8];
        bf16x8 w10 = *(const bf16x8*)&W1s[((tt1 * 2 + 0) * 64 + lane) * 8];
        bf16x8 w11 = *(const bf16x8*)&W1s[((tt1 * 2 + 1) * 64 + lane) * 8];
        n0 = __builtin_amdgcn_mfma_f32_32x32x16_bf16(a0T, w00, n0, 0, 0, 0);
        n0 = __builtin_amdgcn_mfma_f32_32x32x16_bf16(a1T, w01, n0, 0, 0, 0);
        n1 = __builtin_amdgcn_mfma_f32_32x32x16_bf16(a0T, w10, n1, 0, 0, 0);
        n1 = __builtin_amdgcn_mfma_f32_32x32x16_bf16(a1T, w11, n1, 0, 0, 0);
        bf16x8 z00 = *(const bf16x8*)&smZ[zb + n0off];
        bf16x8 z01 = *(const bf16x8*)&smZ[zb + n0off + 16];
        bf16x8 z10 = *(const bf16x8*)&smZ[zb + n1off];
        bf16x8 z11 = *(const bf16x8*)&smZ[zb + n1off + 16];
        n0 = __builtin_amdgcn_mfma_f32_32x32x16_bf16(z00, ilow,  n0, 0, 0, 0);
        n0 = __builtin_amdgcn_mfma_f32_32x32x16_bf16(z01, ihigh, n0, 0, 0, 0);
        n1 = __builtin_amdgcn_mfma_f32_32x32x16_bf16(z10, ilow,  n1, 0, 0, 0);
        n1 = __builtin_amdgcn_mfma_f32_32x32x16_bf16(z11, ihigh, n1, 0, 0, 0);
    }
    __syncthreads();                     // smZ node frag reads done before in-place silu

    // silu -> smH (aliases smZ)
    #pragma unroll
    for (int r = 0; r < 16; ++r) {
        int er = (r & 3) + 8 * (r >> 2) + rowbase;
        smH[er * SZ2 + wv * 32 + lo]       = f2bf_hu(silu_f(n0[r]));
        smH[er * SZ2 + (wv + 4) * 32 + lo] = f2bf_hu(silu_f(n1[r]));
    }
    __syncthreads();                     // smH complete

    // ---- GEMM2: [32 x 256] @ [256 x 128]; wave = 1 d-tile; depth-2 prefetch ----
    {
        const int d = wv * 32 + lo;
        f32x16 acc;
        float bb = bn2[d];
        #pragma unroll
        for (int r = 0; r < 16; ++r) acc[r] = bb;
        const int hoff = lo * SZ2 + hi * 8;
        const int wb = wv * (16 * 64 * 8) + lane * 8;
        bf16x8 bs2[2];
        bs2[0] = *(const bf16x8*)&W2s[wb];
        #pragma unroll
        for (int step = 0; step < 16; ++step) {
            const int cur = step & 1, nxt = cur ^ 1;
            if (step + 1 < 16)
                bs2[nxt] = *(const bf16x8*)&W2s[wb + (step + 1) * 512];
            bf16x8 af = *(const bf16x8*)&smH[hoff + step * 16];
            acc = __builtin_amdgcn_mfma_f32_32x32x16_bf16(af, bs2[cur], acc, 0, 0, 0);
        }
        __syncthreads();                 // smH reads done before smM overwrite
        #pragma unroll
        for (int r = 0; r < 16; ++r) {
            int er = (r & 3) + 8 * (r >> 2) + rowbase;
            smM[er * MSTR + d] = acc[r];
        }
    }
    __syncthreads();

    // ---- run-reduction over sorted dst; interior RMW / boundary atomics ----
    {
        const int g = t >> 5;            // 8 edge-strided groups
        const int d4 = (t & 31) * 4;
        for (int e0 = g; e0 < TE; e0 += 8) {
            if (e0 > 0 && didx[e0] == didx[e0 - 1]) continue;
            float4 s = *(const float4*)&smM[e0 * MSTR + d4];
            int er = e0 + 1;
            while (er < TE && didx[er] == didx[e0]) {
                float4 v = *(const float4*)&smM[er * MSTR + d4];
                s.x += v.x; s.y += v.y; s.z += v.z; s.w += v.w;
                ++er;
            }
            float* dp = &out[didx[e0] * NODE_DIM + d4];
            if (e0 > 0 && er < TE) {
                float4 cur = *(const float4*)dp;
                cur.x += s.x; cur.y += s.y; cur.z += s.z; cur.w += s.w;
                *(float4*)dp = cur;
            } else {
                atomicAdd(dp + 0, s.x); atomicAdd(dp + 1, s.y);
                atomicAdd(dp + 2, s.z); atomicAdd(dp + 3, s.w);
            }
        }
    }
    if (t < TE) {
        int e0 = t;
        if (e0 == 0 || didx[e0] != didx[e0 - 1]) {
            float sx = cxyz[e0], sy = cxyz[TE + e0], sz = cxyz[2 * TE + e0];
            int er = e0 + 1;
            while (er < TE && didx[er] == didx[e0]) {
                sx += cxyz[er]; sy += cxyz[TE + er]; sz += cxyz[2 * TE + er];
                ++er;
            }
            float* xo = out + N_NODES * NODE_DIM + didx[e0] * 3;
            if (e0 > 0 && er < TE) {
                xo[0] += sx; xo[1] += sy; xo[2] += sz;
            } else {
                atomicAdd(xo + 0, sx); atomicAdd(xo + 1, sy); atomicAdd(xo + 2, sz);
            }
        }
    }
}

// fallback: R6 kernel (TE=32, split accumulator), used when ws can't host tables.
__global__ __launch_bounds__(256, 6)
void egnn_mfma_kernel(const float* __restrict__ h, const float* __restrict__ x,
                      const void* __restrict__ ei, const float* __restrict__ dist,
                      const float* __restrict__ We1, const float* __restrict__ be1,
                      const float* __restrict__ bn2, const float* __restrict__ Wc2,
                      const float* __restrict__ biasC,
                      const unsigned short* __restrict__ W1s,
                      const unsigned short* __restrict__ W2s,
                      const int* __restrict__ perm,
                      const unsigned short* __restrict__ hbf,
                      float* __restrict__ out)
{
    __shared__ unsigned short smA[TE * ASTR];
    __shared__ int sidx[TE], didx[TE], eidx[TE];
    __shared__ float cw_s[TE];
    __shared__ float cxyz[3 * TE];

    unsigned short* smH2 = smA;
    float* smM = (float*)smA;

    const int t = threadIdx.x;
    const int lane = t & 63;
    const int wv = t >> 6;
    const int lo = lane & 31;
    const int hi = lane >> 5;
    const int swz = ((blockIdx.x & 7) * (NBLK / 8)) + (blockIdx.x >> 3);
    const int ebase = swz * TE;
    const int is64 = detect_is64(ei, t);

    if (t < 2 * TE) {
        int e = t & (TE - 1);
        int eid = perm[ebase + e];
        int which = t >> 5;
        long long pos = (long long)which * N_EDGES + eid;
        int idx = is64 ? (int)((const long long*)ei)[pos] : ((const int*)ei)[pos];
        if (which == 0) { sidx[e] = idx; eidx[e] = eid; }
        else didx[e] = idx;
        if (t < TE) cw_s[t] = 0.0f;
    }
    __syncthreads();

    if (hbf != nullptr) {
        #pragma unroll
        for (int it = 0; it < 4; ++it) {
            int id = it * 256 + t;
            int g = id & 15;
            int half = (id >> 4) & 1;
            int e = id >> 5;
            int node = half ? didx[e] : sidx[e];
            uint4 v = *(const uint4*)&hbf[node * NODE_DIM + 8 * g];
            *(uint4*)&smA[e * ASTR + half * NODE_DIM + 8 * g] = v;
        }
    } else {
        #pragma unroll
        for (int it = 0; it < 4; ++it) {
            int id = it * 256 + t;
            int g8 = id & 15;
            int half = (id >> 4) & 1;
            int e = id >> 5;
            int node = half ? didx[e] : sidx[e];
            const float4* p = (const float4*)&h[node * NODE_DIM + 8 * g8];
            float4 v0 = p[0], v1 = p[1];
            unsigned int a0 = pkbf(v0.x, v0.y), a1 = pkbf(v0.z, v0.w);
            unsigned int a2 = pkbf(v1.x, v1.y), a3 = pkbf(v1.z, v1.w);
            *(uint4*)&smA[e * ASTR + half * NODE_DIM + 8 * g8] = make_uint4(a0, a1, a2, a3);
        }
    }
    {
        int e = t >> 3;
        int j4 = (t & 7) * 4;
        float d = dist[eidx[e]];
        float s0 = silu_f(d * We1[j4 + 0] + be1[j4 + 0]);
        float s1 = silu_f(d * We1[j4 + 1] + be1[j4 + 1]);
        float s2 = silu_f(d * We1[j4 + 2] + be1[j4 + 2]);
        float s3 = silu_f(d * We1[j4 + 3] + be1[j4 + 3]);
        *(uint2*)&smA[e * ASTR + 2 * NODE_DIM + j4] = make_uint2(pkbf(s0, s1), pkbf(s2, s3));
    }
    if (t < TE) {
        int s = sidx[t], dn = didx[t];
        float dx = x[s * 3 + 0] - x[dn * 3 + 0];
        float dy = x[s * 3 + 1] - x[dn * 3 + 1];
        float dz = x[s * 3 + 2] - x[dn * 3 + 2];
        float len = fmaxf(sqrtf(dx * dx + dy * dy + dz * dz), 1e-8f);
        float inv = 1.0f / len;
        cxyz[t] = dx * inv; cxyz[TE + t] = dy * inv; cxyz[2 * TE + t] = dz * inv;
    }
    __syncthreads();

    const int rowbase = 4 * hi;

    {
        f32x16 c0, c1;
        {
            float b0 = biasC[256 + wv * 32 + lo];
            float b1 = biasC[256 + (wv + 4) * 32 + lo];
            #pragma unroll
            for (int r = 0; r < 16; ++r) { c0[r] = b0; c1[r] = b1; }
        }
        {
            const int ao = lo * ASTR + hi * 8;
            const int TS = 18 * 64 * 8;
            const int q0 = (8 + wv) * TS + lane * 8;
            const int q1 = (12 + wv) * TS + lane * 8;
            bf16x8 p0[2], p1[2];
            p0[0] = *(const bf16x8*)&W1s[q0];
            p1[0] = *(const bf16x8*)&W1s[q1];
            #pragma unroll
            for (int step = 0; step < 18; ++step) {
                const int cur = step & 1, nxt = cur ^ 1;
                if (step + 1 < 18) {
                    p0[nxt] = *(const bf16x8*)&W1s[q0 + (step + 1) * 512];
                    p1[nxt] = *(const bf16x8*)&W1s[q1 + (step + 1) * 512];
                }
                bf16x8 f = *(const bf16x8*)&smA[ao + step * 16];
                c0 = __builtin_amdgcn_mfma_f32_32x32x16_bf16(f, p0[cur], c0, 0, 0, 0);
                c1 = __builtin_amdgcn_mfma_f32_32x32x16_bf16(f, p1[cur], c1, 0, 0, 0);
            }
        }
        float w0 = Wc2[wv * 32 + lo];
        float w1 = Wc2[(wv + 4) * 32 + lo];
        float p[16];
        #pragma unroll
        for (int r = 0; r < 16; ++r)
            p[r] = silu_f(c0[r]) * w0 + silu_f(c1[r]) * w1;
        #pragma unroll
        for (int off = 1; off < 32; off <<= 1) {
            #pragma unroll
            for (int r = 0; r < 16; ++r) p[r] += __shfl_xor(p[r], off);
        }
        if (lo == 0) {
            #pragma unroll
            for (int r = 0; r < 16; ++r)
                atomicAdd(&cw_s[(r & 3) + 8 * (r >> 2) + rowbase], p[r]);
        }
    }

    f32x16 a0, a1;
    {
        float b0 = biasC[wv * 32 + lo];
        float b1 = biasC[(wv + 4) * 32 + lo];
        #pragma unroll
        for (int r = 0; r < 16; ++r) { a0[r] = b0; a1[r] = b1; }
        const int ao = lo * ASTR + hi * 8;
        const int TS = 18 * 64 * 8;
        const int q0 = (wv) * TS + lane * 8;
        const int q1 = (wv + 4) * TS + lane * 8;
        bf16x8 p0[2], p1[2];
        p0[0] = *(const bf16x8*)&W1s[q0];
        p1[0] = *(const bf16x8*)&W1s[q1];
        #pragma unroll
        for (int step = 0; step < 18; ++step) {
            const int cur = step & 1, nxt = cur ^ 1;
            if (step + 1 < 18) {
                p0[nxt] = *(const bf16x8*)&W1s[q0 + (step + 1) * 512];
                p1[nxt] = *(const bf16x8*)&W1s[q1 + (step + 1) * 512];
            }
            bf16x8 f = *(const bf16x8*)&smA[ao + step * 16];
            a0 = __builtin_amdgcn_mfma_f32_32x32x16_bf16(f, p0[cur], a0, 0, 0, 0);
            a1 = __builtin_amdgcn_mfma_f32_32x32x16_bf16(f, p1[cur], a1, 0, 0, 0);
        }
    }
    __syncthreads();

    {
        const int jb0 = (wv    ) * 32 + lo;
        const int jb1 = (wv + 4) * 32 + lo;
        #pragma unroll
        for (int r = 0; r < 16; ++r) {
            int er = (r & 3) + 8 * (r >> 2) + rowbase;
            smH2[er * HSTR + jb0] = f2bf_hu(silu_f(a0[r]));
            smH2[er * HSTR + jb1] = f2bf_hu(silu_f(a1[r]));
        }
    }
    if (t < TE) {
        float w = cw_s[t];
        cxyz[t] *= w; cxyz[TE + t] *= w; cxyz[2 * TE + t] *= w;
    }
    __syncthreads();

    {
        const int d = wv * 32 + lo;
        f32x16 acc;
        float bb = bn2[d];
        #pragma unroll
        for (int r = 0; r < 16; ++r) acc[r] = bb;
        const int hoff = lo * HSTR + hi * 8;
        const int wb = wv * (16 * 64 * 8) + lane * 8;
        bf16x8 bs2[2];
        bs2[0] = *(const bf16x8*)&W2s[wb];
        #pragma unroll
        for (int step = 0; step < 16; ++step) {
            const int cur = step & 1, nxt = cur ^ 1;
            if (step + 1 < 16)
                bs2[nxt] = *(const bf16x8*)&W2s[wb + (step + 1) * 512];
            bf16x8 af = *(const bf16x8*)&smH2[hoff + step * 16];
            acc = __builtin_amdgcn_mfma_f32_32x32x16_bf16(af, bs2[cur], acc, 0, 0, 0);
        }
        __syncthreads();
        #pragma unroll
        for (int r = 0; r < 16; ++r) {
            int er = (r & 3) + 8 * (r >> 2) + rowbase;
            smM[er * MSTR + d] = acc[r];
        }
    }
    __syncthreads();

    {
        const int g = t >> 5;
        const int d4 = (t & 31) * 4;
        for (int e0 = g; e0 < TE; e0 += 8) {
            if (e0 > 0 && didx[e0] == didx[e0 - 1]) continue;
            float4 s = *(const float4*)&smM[e0 * MSTR + d4];
            int er = e0 + 1;
            while (er < TE && didx[er] == didx[e0]) {
                float4 v = *(const float4*)&smM[er * MSTR + d4];
                s.x += v.x; s.y += v.y; s.z += v.z; s.w += v.w;
                ++er;
            }
            float* dp = &out[didx[e0] * NODE_DIM + d4];
            if (e0 > 0 && er < TE) {
                float4 cur = *(const float4*)dp;
                cur.x += s.x; cur.y += s.y; cur.z += s.z; cur.w += s.w;
                *(float4*)dp = cur;
            } else {
                atomicAdd(dp + 0, s.x); atomicAdd(dp + 1, s.y);
                atomicAdd(dp + 2, s.z); atomicAdd(dp + 3, s.w);
            }
        }
    }
    if (t < TE) {
        int e0 = t;
        if (e0 == 0 || didx[e0] != didx[e0 - 1]) {
            float sx = cxyz[e0], sy = cxyz[TE + e0], sz = cxyz[2 * TE + e0];
            int er = e0 + 1;
            while (er < TE && didx[er] == didx[e0]) {
                sx += cxyz[er]; sy += cxyz[TE + er]; sz += cxyz[2 * TE + er];
                ++er;
            }
            float* xo = out + N_NODES * NODE_DIM + didx[e0] * 3;
            if (e0 > 0 && er < TE) {
                xo[0] += sx; xo[1] += sy; xo[2] += sz;
            } else {
                atomicAdd(xo + 0, sx); atomicAdd(xo + 1, sy); atomicAdd(xo + 2, sz);
            }
        }
    }
}

extern "C" void kernel_launch(void* const* d_in, const int* in_sizes, int n_in,
                              void* d_out, int out_size, void* d_ws, size_t ws_size,
                              hipStream_t stream) {
    const float* h    = (const float*)d_in[0];
    const float* x    = (const float*)d_in[1];
    const void*  ei   = d_in[2];
    const float* dist = (const float*)d_in[3];
    const float* We1  = (const float*)d_in[4];
    const float* be1  = (const float*)d_in[5];
    const float* We2  = (const float*)d_in[6];
    const float* be2  = (const float*)d_in[7];
    const float* Wn1  = (const float*)d_in[8];
    const float* bn1  = (const float*)d_in[9];
    const float* Wn2  = (const float*)d_in[10];
    const float* bn2  = (const float*)d_in[11];
    const float* Wc1  = (const float*)d_in[12];
    const float* bc1  = (const float*)d_in[13];
    const float* Wc2  = (const float*)d_in[14];
    float* out = (float*)d_out;

    float* biasC = (float*)((char*)d_ws + WS_BIAS_OFF);
    unsigned short* W1s = (unsigned short*)((char*)d_ws + WS_W1S_OFF);
    unsigned short* W2s = (unsigned short*)((char*)d_ws + WS_W2S_OFF);
    int* counts   = (int*)((char*)d_ws + WS_CNT_OFF);
    int* cursor   = (int*)((char*)d_ws + WS_CUR_OFF);
    int* perm     = (int*)((char*)d_ws + WS_PERM_OFF);
    unsigned short* hbf = (ws_size >= (size_t)WS_HBF_END)
                        ? (unsigned short*)((char*)d_ws + WS_HBF_OFF) : nullptr;
    int use_pp = (ws_size >= (size_t)WS_PD_END && hbf != nullptr) ? 1 : 0;
    unsigned short* psrc = use_pp ? (unsigned short*)((char*)d_ws + WS_PS_OFF) : nullptr;
    unsigned short* pdst = use_pp ? (unsigned short*)((char*)d_ws + WS_PD_OFF) : nullptr;

    hipMemsetAsync(counts, 0, N_NODES * sizeof(int), stream);

    prep_hist_kernel<<<PREP_TOT / 256, 256, 0, stream>>>(
        h, x, ei, We2, be2, Wn1, bn1, Wn2, Wc1, bc1,
        out, biasC, W1s, W2s, counts, hbf, use_pp);

    scan_fused_kernel<<<128, 256, 0, stream>>>(counts, cursor);

    if (use_pp) {
        place_nterm_kernel<<<PLACE_BLKS + NT_BLKS, 256, 0, stream>>>(
            ei, cursor, perm, hbf, W1s, psrc, pdst);
        egnn_pp_kernel<<<NBLK, 256, 0, stream>>>(
            x, ei, dist, We1, be1, bn2, Wc2, biasC, W1s, W2s, perm, psrc, pdst, out);
    } else {
        place_kernel<<<PLACE_BLKS, 256, 0, stream>>>(ei, cursor, perm);
        egnn_mfma_kernel<<<NBLK, 256, 0, stream>>>(
            h, x, ei, dist, We1, be1, bn2, Wc2, biasC, W1s, W2s, perm, hbf, out);
    }
}